// Round 3
// baseline (6833.716 us; speedup 1.0000x reference)
//
#include <hip/hip_runtime.h>
#include <hip/hip_bf16.h>
#include <math.h>

// ============================================================================
// PPGPeakPerformer forward on MI355X (gfx950)
// B=32 S=4096 D=256 DH=128 H=8 HD=32 F=64 L=4
// Batch-chunked (runtime Bc chosen to fit ws_size). Fused q/k RF projection:
// softplus((x@Wq+b)@rf) == softplus(x@(Wq@rf)+(b@rf)) -> one N=1280 GEMM.
// bf16 MFMA GEMMs (128x128 tile, BK=64, XOR-swizzled LDS via pre-swizzled
// global source + global_load_lds dwordx4 direct staging, weights [N][K]);
// convs as im2col GEMMs over zero-padded channel-contiguous buffers;
// deterministic chunked kv reduction; combine via MFMA with denom column.
// ============================================================================

typedef __bf16 bf16_t;
typedef __bf16 bf16x8 __attribute__((ext_vector_type(8)));
typedef __bf16 bf16x4 __attribute__((ext_vector_type(4)));
typedef float  f32x4  __attribute__((ext_vector_type(4)));

#define DEV __device__ __forceinline__

DEV float geluf(float v) { return 0.5f * v * (1.f + erff(v * 0.70710678118654752440f)); }
DEV float softplusf(float v) { return v > 20.f ? v : log1pf(expf(v)); }

// Direct global->LDS 16B staging (no VGPR round-trip). LDS dest must be
// wave-uniform base; HW writes base + lane*16 (rule 21: linear dest).
DEV void gload16(const bf16_t* g, bf16_t* l) {
  __builtin_amdgcn_global_load_lds(
      (const __attribute__((address_space(1))) void*)g,
      (__attribute__((address_space(3))) void*)l, 16, 0, 0);
}

// ---------------------------------------------------------------------------
// GEMM: C[m,n] = sum_k A[m,k]*Bt[n,k].  A bf16 (batched rows), Bt bf16 [N][K].
// Row r -> b = r/rpb, s = r%rpb; A elem = A + b*a_bstride + s*lda + k.
// C index  = b*c_bstride + (s + c_roff)*ldc + col.
// EPI: 1 = +bias +resid -> fp32   (O-proj, FF2; resid==Cout, elementwise safe)
//      2 = gelu(+bias) -> bf16    (FF1)
//      3 = gelu(scale*x+bias)+pe -> fp32  (embed conv2)
//      4 = gelu(scale*x+bias) -> bf16     (decoder conv1)
//      5 = col<1024 ? softplus(+bias) : (+bias) -> bf16   (fused qp/kp/v)
// Staging: wave w owns rows [32w,32w+32) of both As/Bs. Per 8-row group the
// lane's global source slot is XORed by its row-in-group (sr == r&7), so LDS
// ends up XOR-swizzled (byte ^= (r&7)<<4) while the gload_lds dest is linear.
// ---------------------------------------------------------------------------
template <int EPI>
__global__ __launch_bounds__(256, 2)
void gemm_bf16(const bf16_t* __restrict__ A, const bf16_t* __restrict__ Bt,
               void* Cout, const float* __restrict__ bias,
               const float* __restrict__ scale, const float* resid,
               const float* __restrict__ pe,
               int K, int lda, long a_bstride, int rpb,
               int N, int ldc, long c_bstride, int c_roff)
{
  __shared__ bf16_t As[128 * 64];
  __shared__ bf16_t Bs[128 * 64];
  const int t = threadIdx.x;
  const int lane = t & 63;
  const int w = t >> 6;
  const int wm = w >> 1, wn = w & 1;
  const long m0 = (long)blockIdx.x * 128;
  const int n0 = blockIdx.y * 128;
  const int b = (int)(m0 / rpb);
  const int s_base = (int)(m0 % rpb);
  const bf16_t* Ab = A + (long)b * a_bstride + (long)s_base * lda;
  const bf16_t* Bb = Bt + (long)n0 * K;

  // staging source bases (pre-swizzled slot)
  const int sr = lane >> 3;                 // row-in-8-group == r&7
  const int soff = ((lane & 7) ^ sr) * 8;   // element offset within 64-elem row
  const bf16_t* aSrc = Ab + (long)(w * 32 + sr) * lda + soff;
  const bf16_t* bSrc = Bb + (long)(w * 32 + sr) * K + soff;
  bf16_t* aDst = As + w * 32 * 64;
  bf16_t* bDst = Bs + w * 32 * 64;

  f32x4 acc[4][4];
#pragma unroll
  for (int i = 0; i < 4; i++)
#pragma unroll
    for (int j = 0; j < 4; j++) acc[i][j] = (f32x4){0.f, 0.f, 0.f, 0.f};

  for (int k0 = 0; k0 < K; k0 += 64) {
    if (k0) __syncthreads();  // previous tile's fragment reads complete
#pragma unroll
    for (int i = 0; i < 4; i++) {
      gload16(aSrc + k0 + (long)(i * 8) * lda, aDst + i * 8 * 64);
      gload16(bSrc + k0 + (long)(i * 8) * K,  bDst + i * 8 * 64);
    }
    __syncthreads();  // drains vmcnt(0): staged tile visible
#pragma unroll
    for (int kt = 0; kt < 2; kt++) {
      const int kb = kt * 64 + (lane >> 4) * 16;
      bf16x8 af[4], bfr[4];
#pragma unroll
      for (int i = 0; i < 4; i++) {
        int rA = wm * 64 + i * 16 + (lane & 15);
        af[i] = *(const bf16x8*)((const char*)As + rA * 128 + (kb ^ ((rA & 7) << 4)));
        int rB = wn * 64 + i * 16 + (lane & 15);
        bfr[i] = *(const bf16x8*)((const char*)Bs + rB * 128 + (kb ^ ((rB & 7) << 4)));
      }
#pragma unroll
      for (int mi = 0; mi < 4; mi++)
#pragma unroll
        for (int ni = 0; ni < 4; ni++)
          acc[mi][ni] = __builtin_amdgcn_mfma_f32_16x16x32_bf16(af[mi], bfr[ni], acc[mi][ni], 0, 0, 0);
    }
  }

  const int colbase = n0 + wn * 64 + (lane & 15);
  float bias_r[4], scale_r[4];
#pragma unroll
  for (int ni = 0; ni < 4; ni++) {
    int col = colbase + ni * 16;
    bias_r[ni] = bias[col];
    scale_r[ni] = (EPI == 3 || EPI == 4) ? scale[col] : 0.f;
  }
#pragma unroll
  for (int mi = 0; mi < 4; mi++) {
#pragma unroll
    for (int j = 0; j < 4; j++) {
      int row = wm * 64 + mi * 16 + ((lane >> 4) << 2) + j;
      long s = s_base + row;
      long cro = (long)b * c_bstride + (s + c_roff) * (long)ldc;
#pragma unroll
      for (int ni = 0; ni < 4; ni++) {
        int col = colbase + ni * 16;
        float v = acc[mi][ni][j];
        if constexpr (EPI == 1) {
          v += bias_r[ni] + resid[cro + col];
          ((float*)Cout)[cro + col] = v;
        } else if constexpr (EPI == 2) {
          v = geluf(v + bias_r[ni]);
          ((bf16_t*)Cout)[cro + col] = (bf16_t)v;
        } else if constexpr (EPI == 3) {
          v = geluf(v * scale_r[ni] + bias_r[ni]) + pe[s * 256 + col];
          ((float*)Cout)[cro + col] = v;
        } else if constexpr (EPI == 4) {
          v = geluf(v * scale_r[ni] + bias_r[ni]);
          ((bf16_t*)Cout)[cro + col] = (bf16_t)v;
        } else {  // 5
          v += bias_r[ni];
          if (col < 1024) v = softplusf(v);
          ((bf16_t*)Cout)[cro + col] = (bf16_t)v;
        }
      }
    }
  }
}

// ---------------------------------------------------------------------------
// LayerNorm over D=256, fp32 in -> bf16 out. 4 rows/block (1 wave per row).
// ---------------------------------------------------------------------------
__global__ __launch_bounds__(256)
void ln_kernel(const float* __restrict__ h, const float* __restrict__ g,
               const float* __restrict__ bta, bf16_t* __restrict__ out)
{
  int t = threadIdx.x;
  int lane = t & 63;
  long row = (long)blockIdx.x * 4 + (t >> 6);
  const float* hp = h + row * 256 + lane * 4;
  float4 v = *(const float4*)hp;
  float s = v.x + v.y + v.z + v.w;
  float q = v.x * v.x + v.y * v.y + v.z * v.z + v.w * v.w;
#pragma unroll
  for (int m = 32; m >= 1; m >>= 1) {
    s += __shfl_xor(s, m);
    q += __shfl_xor(q, m);
  }
  float mean = s * 0.00390625f;
  float var = q * 0.00390625f - mean * mean;
  float rstd = rsqrtf(var + 1e-5f);
  int c = lane * 4;
  float4 gv = *(const float4*)(g + c);
  float4 bv = *(const float4*)(bta + c);
  bf16x4 o;
  o[0] = (bf16_t)((v.x - mean) * rstd * gv.x + bv.x);
  o[1] = (bf16_t)((v.y - mean) * rstd * gv.y + bv.y);
  o[2] = (bf16_t)((v.z - mean) * rstd * gv.z + bv.z);
  o[3] = (bf16_t)((v.w - mean) * rstd * gv.w + bv.w);
  *(bf16x4*)(out + row * 256 + c) = o;
}

// ---------------------------------------------------------------------------
// Embedding conv1: x[Bc,S] -> gelu(bn(conv1d k=7 pad=3)) -> h1p[Bc,S+4,128]
// ---------------------------------------------------------------------------
__global__ __launch_bounds__(256)
void conv1_kernel(const float* __restrict__ x, const float* __restrict__ w1,
                  const float* __restrict__ sc, const float* __restrict__ sb,
                  bf16_t* __restrict__ h1p)
{
  int b = blockIdx.x >> 6;
  int s0 = (blockIdx.x & 63) << 6;
  __shared__ float xs[70];
  __shared__ float ws[896];
  int t = threadIdx.x;
  if (t < 70) {
    int s = s0 + t - 3;
    xs[t] = (s >= 0 && s < 4096) ? x[(long)b * 4096 + s] : 0.f;
  }
  for (int i = t; i < 896; i += 256) ws[i] = w1[i];
  __syncthreads();
  int c = t & 127, so = t >> 7;
  float wr[7];
#pragma unroll
  for (int k = 0; k < 7; k++) wr[k] = ws[c * 7 + k];
  float scl = sc[c], sbv = sb[c];
  for (int p = 0; p < 32; p++) {
    int sl = p * 2 + so;
    float a = 0.f;
#pragma unroll
    for (int k = 0; k < 7; k++) a += xs[sl + k] * wr[k];
    a = geluf(a * scl + sbv);
    h1p[((long)b * 4100 + s0 + sl + 2) * 128 + c] = (bf16_t)a;
  }
}

// ---------------------------------------------------------------------------
// kv partial: per (b,h,chunk of 512 s): acc[f][d] += kp[s,f]*v[s,d]; +ksum.
// kp/v read from fused qpkpv rows (stride 1280: [qp 0..511 | kp 512..1023 |
// v 1024..1279]). Deterministic fixed partial order.
// ---------------------------------------------------------------------------
__global__ __launch_bounds__(256)
void kv_partial(const bf16_t* __restrict__ qpkpv,
                float* __restrict__ pkv, float* __restrict__ pks)
{
  int bh = blockIdx.x >> 3, ch = blockIdx.x & 7;
  int b = bh >> 3, hh = bh & 7;
  int s0 = ch * 512;
  __shared__ float kps[32 * 64];
  __shared__ float vs[32 * 32];
  int t = threadIdx.x;
  int f = t & 63, dg = t >> 6;
  float acc[8] = {0.f, 0.f, 0.f, 0.f, 0.f, 0.f, 0.f, 0.f};
  float ks = 0.f;
  const int row = t >> 3, slot8 = (t & 7) * 8, slot4 = (t & 7) * 4;
  for (int sb = 0; sb < 512; sb += 32) {
    __syncthreads();
    {
      const bf16_t* rowp = qpkpv + ((long)b * 4096 + s0 + sb + row) * 1280;
      bf16x8 k8 = *(const bf16x8*)(rowp + 512 + hh * 64 + slot8);
#pragma unroll
      for (int j = 0; j < 8; j++) kps[row * 64 + slot8 + j] = (float)k8[j];
      bf16x4 v4 = *(const bf16x4*)(rowp + 1024 + hh * 32 + slot4);
#pragma unroll
      for (int j = 0; j < 4; j++) vs[row * 32 + slot4 + j] = (float)v4[j];
    }
    __syncthreads();
#pragma unroll 4
    for (int s = 0; s < 32; s++) {
      float kval = kps[s * 64 + f];
      float4 v0 = *(const float4*)&vs[s * 32 + dg * 8];
      float4 v1 = *(const float4*)&vs[s * 32 + dg * 8 + 4];
      acc[0] += kval * v0.x; acc[1] += kval * v0.y;
      acc[2] += kval * v0.z; acc[3] += kval * v0.w;
      acc[4] += kval * v1.x; acc[5] += kval * v1.y;
      acc[6] += kval * v1.z; acc[7] += kval * v1.w;
      ks += kval;
    }
  }
  long o = (long)blockIdx.x * 2048 + f * 32 + dg * 8;
#pragma unroll
  for (int j = 0; j < 8; j++) pkv[o + j] = acc[j];
  if (dg == 0) pks[blockIdx.x * 64 + f] = ks;
}

__global__ __launch_bounds__(256)
void kv_reduce(const float* __restrict__ pkv, const float* __restrict__ pks,
               float* __restrict__ kv, float* __restrict__ ksum, int nbh)
{
  long idx = (long)blockIdx.x * 256 + threadIdx.x;  // nbh*2048
  {
    int bh = (int)(idx >> 11), fd = (int)(idx & 2047);
    float s = 0.f;
#pragma unroll
    for (int ch = 0; ch < 8; ch++) s += pkv[((long)(bh * 8 + ch)) * 2048 + fd];
    kv[idx] = s;
  }
  if (idx < (long)nbh * 64) {
    int bh = (int)(idx >> 6), f = (int)(idx & 63);
    float s = 0.f;
#pragma unroll
    for (int ch = 0; ch < 8; ch++) s += pks[(bh * 8 + ch) * 64 + f];
    ksum[idx] = s;
  }
}

// ---------------------------------------------------------------------------
// combine: ao[s, h*32+d] = (qp[s,:] @ kv[:,d]) / (qp[s,:]@ksum + 1e-8)
// MFMA with B = [kv^T | ksum | 0pad] (48 cols), denom broadcast via shfl.
// ---------------------------------------------------------------------------
__global__ __launch_bounds__(256, 2)
void combine_mfma(const bf16_t* __restrict__ qpkpv, const float* __restrict__ kv,
                  const float* __restrict__ ksum, bf16_t* __restrict__ ao)
{
  int bh = blockIdx.x >> 5;
  int s0 = (blockIdx.x & 31) << 7;
  int b = bh >> 3, hh = bh & 7;
  __shared__ bf16_t A_s[128 * 72];
  __shared__ bf16_t B_s[48 * 72];
  int t = threadIdx.x;
  for (int g = t; g < 1024; g += 256) {
    int row = g >> 3, slot = (g & 7) * 8;
    *(bf16x8*)&A_s[row * 72 + slot] =
        *(const bf16x8*)(qpkpv + ((long)b * 4096 + s0 + row) * 1280 + hh * 64 + slot);
  }
  for (int i = t; i < 2048; i += 256) {
    int f = i >> 5, d = i & 31;
    B_s[d * 72 + f] = (bf16_t)kv[(long)bh * 2048 + i];
  }
  if (t < 64) B_s[32 * 72 + t] = (bf16_t)ksum[bh * 64 + t];
  for (int i = t; i < 960; i += 256) {
    int n = 33 + (i >> 6), f = i & 63;
    B_s[n * 72 + f] = (bf16_t)0.f;
  }
  __syncthreads();
  int lane = t & 63, w = t >> 6;
  f32x4 acc[2][3];
#pragma unroll
  for (int i = 0; i < 2; i++)
#pragma unroll
    for (int j = 0; j < 3; j++) acc[i][j] = (f32x4){0.f, 0.f, 0.f, 0.f};
#pragma unroll
  for (int kt = 0; kt < 2; kt++) {
    int ko = kt * 32 + (lane >> 4) * 8;
    bf16x8 a[2], bb[3];
#pragma unroll
    for (int i = 0; i < 2; i++)
      a[i] = *(const bf16x8*)&A_s[(w * 32 + i * 16 + (lane & 15)) * 72 + ko];
#pragma unroll
    for (int i = 0; i < 3; i++)
      bb[i] = *(const bf16x8*)&B_s[(i * 16 + (lane & 15)) * 72 + ko];
#pragma unroll
    for (int mi = 0; mi < 2; mi++)
#pragma unroll
      for (int ni = 0; ni < 3; ni++)
        acc[mi][ni] = __builtin_amdgcn_mfma_f32_16x16x32_bf16(a[mi], bb[ni], acc[mi][ni], 0, 0, 0);
  }
  long sbase = (long)b * 4096 + s0;
#pragma unroll
  for (int mi = 0; mi < 2; mi++)
#pragma unroll
    for (int j = 0; j < 4; j++) {
      int r = w * 32 + mi * 16 + ((lane >> 4) << 2) + j;
      float den = __shfl(acc[mi][2][j], (lane & 48)) + 1e-8f;
#pragma unroll
      for (int ni = 0; ni < 2; ni++) {
        int d = ni * 16 + (lane & 15);
        ao[(sbase + r) * 256 + hh * 32 + d] = (bf16_t)(acc[mi][ni][j] / den);
      }
    }
}

// ---------------------------------------------------------------------------
// h fp32 -> h_padded bf16 [Bc, S+4, 256] (rows offset +2)
// ---------------------------------------------------------------------------
__global__ __launch_bounds__(256)
void cast_pad(const float* __restrict__ h, bf16_t* __restrict__ hp)
{
  long i8 = ((long)blockIdx.x * 256 + threadIdx.x) * 8;
  long r = i8 >> 8;
  int c = (int)(i8 & 255);
  int b = (int)(r >> 12), s = (int)(r & 4095);
  float4 v0 = *(const float4*)(h + i8);
  float4 v1 = *(const float4*)(h + i8 + 4);
  bf16x8 o;
  o[0] = (bf16_t)v0.x; o[1] = (bf16_t)v0.y; o[2] = (bf16_t)v0.z; o[3] = (bf16_t)v0.w;
  o[4] = (bf16_t)v1.x; o[5] = (bf16_t)v1.y; o[6] = (bf16_t)v1.z; o[7] = (bf16_t)v1.w;
  *(bf16x8*)(hp + ((long)b * 4100 + s + 2) * 256 + c) = o;
}

// ---------------------------------------------------------------------------
// Final conv (DH->1, k=3, pad=1) + sigmoid -> out [Bc,S] fp32
// ---------------------------------------------------------------------------
__global__ __launch_bounds__(256)
void conv_final(const bf16_t* __restrict__ hdp, const float* __restrict__ w2,
                const float* __restrict__ b2, float* __restrict__ out)
{
  __shared__ float ws[384];
  int t = threadIdx.x;
  for (int i = t; i < 384; i += 256) ws[i] = w2[i];  // [c][k]
  __syncthreads();
  long idx = (long)blockIdx.x * 256 + t;
  int b = (int)(idx >> 12);
  const bf16_t* base = hdp + ((long)b * 4098 + (idx & 4095)) * 128;
  float a = b2[0];
#pragma unroll
  for (int k = 0; k < 3; k++) {
#pragma unroll
    for (int c8 = 0; c8 < 16; c8++) {
      bf16x8 v = *(const bf16x8*)(base + k * 128 + c8 * 8);
#pragma unroll
      for (int j = 0; j < 8; j++) a += (float)v[j] * ws[(c8 * 8 + j) * 3 + k];
    }
  }
  out[idx] = 1.f / (1.f + expf(-a));
}

// ---------------------------------------------------------------------------
// Prep kernels (once per launch)
// ---------------------------------------------------------------------------
__global__ __launch_bounds__(256)
void prep_weff(const float* __restrict__ wq, const float* __restrict__ wk,
               const float* __restrict__ wv, const float* __restrict__ bq,
               const float* __restrict__ bk, const float* __restrict__ bv,
               const float* __restrict__ rf, bf16_t* __restrict__ weff,
               float* __restrict__ beff)
{
  long idx = (long)blockIdx.x * 256 + threadIdx.x;  // 4*1280*256
  int d = (int)(idx & 255);
  long r = idx >> 8;
  int n = (int)(r % 1280);
  int l = (int)(r / 1280);
  float val;
  if (n < 1024) {
    int qk = n >> 9;
    int h = (n >> 6) & 7;
    int f = n & 63;
    const float* w = qk ? wk : wq;
    const float* rfh = rf + ((long)(l * 8 + h) * 32) * 64 + f;
    const float* wrow = w + ((long)l * 256 + d) * 256 + h * 32;
    float s = 0.f;
#pragma unroll
    for (int hd = 0; hd < 32; hd++) s += wrow[hd] * rfh[hd * 64];
    val = s;
  } else {
    val = wv[((long)l * 256 + d) * 256 + (n - 1024)];
  }
  weff[idx] = (bf16_t)val;
  if (idx < 4 * 1280) {
    int nn = (int)(idx % 1280);
    int ll = (int)(idx / 1280);
    float bvv;
    if (nn < 1024) {
      int qk = nn >> 9;
      int h = (nn >> 6) & 7;
      int f = nn & 63;
      const float* bsrc = qk ? bk : bq;
      float s = 0.f;
      for (int hd = 0; hd < 32; hd++)
        s += bsrc[ll * 256 + h * 32 + hd] * rf[((long)(ll * 8 + h) * 32 + hd) * 64 + f];
      bvv = s;
    } else {
      bvv = bv[ll * 256 + (nn - 1024)];
    }
    beff[idx] = bvv;
  }
}

__global__ __launch_bounds__(256)
void prep_cast_t(const float* __restrict__ src, bf16_t* __restrict__ dst, int K, int N)
{
  long idx = (long)blockIdx.x * 256 + threadIdx.x;  // nmats*N*K
  int k = (int)(idx % K);
  long r = idx / K;
  int n = (int)(r % N);
  int l = (int)(r / N);
  dst[idx] = (bf16_t)src[((long)l * K + k) * N + n];
}

__global__ __launch_bounds__(256)
void prep_conv_t(const float* __restrict__ w, bf16_t* __restrict__ dst, int C, int KW)
{
  long idx = (long)blockIdx.x * 256 + threadIdx.x;  // O*C*KW
  int ckw = C * KW;
  int kk = (int)(idx % ckw);
  int o = (int)(idx / ckw);
  int kw = kk / C, c = kk % C;
  dst[idx] = (bf16_t)w[((long)o * C + c) * KW + kw];
}

__global__ __launch_bounds__(256)
void prep_bn(const float* g1, const float* b1, const float* cb1,
             const float* g2, const float* b2, const float* cb2,
             const float* g3, const float* b3, const float* cb3,
             float* sc1, float* sb1, float* sc2, float* sb2,
             float* sc3, float* sb3)
{
  int t = threadIdx.x;
  const float r = rsqrtf(1.f + 1e-5f);
  if (t < 128) { float s = g1[t] * r; sc1[t] = s; sb1[t] = cb1[t] * s + b1[t]; }
  if (t < 256) { float s = g2[t] * r; sc2[t] = s; sb2[t] = cb2[t] * s + b2[t]; }
  if (t < 128) { float s = g3[t] * r; sc3[t] = s; sb3[t] = cb3[t] * s + b3[t]; }
}

__global__ __launch_bounds__(256)
void pe_fill(float* __restrict__ pe)
{
  long idx = (long)blockIdx.x * 256 + threadIdx.x;  // 4096*256
  int dcol = (int)(idx & 255);
  int s = (int)(idx >> 8);
  int i2 = dcol >> 1;
  float freq = expf(-9.210340371976184f * (float)(2 * i2) / 256.f);
  float a = (float)s * freq;
  pe[idx] = (dcol & 1) ? cosf(a) : sinf(a);
}

// ---------------------------------------------------------------------------
extern "C" void kernel_launch(void* const* d_in, const int* in_sizes, int n_in,
                              void* d_out, int out_size, void* d_ws, size_t ws_size,
                              hipStream_t stream)
{
  (void)in_sizes; (void)n_in; (void)out_size;
  const float* x      = (const float*)d_in[0];
  const float* emb_w1 = (const float*)d_in[1];
  const float* emb_b1 = (const float*)d_in[2];
  const float* bn1_g  = (const float*)d_in[3];
  const float* bn1_b  = (const float*)d_in[4];
  const float* emb_w2 = (const float*)d_in[5];
  const float* emb_b2 = (const float*)d_in[6];
  const float* bn2_g  = (const float*)d_in[7];
  const float* bn2_b  = (const float*)d_in[8];
  const float* wq     = (const float*)d_in[9];
  const float* bq     = (const float*)d_in[10];
  const float* wk     = (const float*)d_in[11];
  const float* bk     = (const float*)d_in[12];
  const float* wv     = (const float*)d_in[13];
  const float* bv     = (const float*)d_in[14];
  const float* wo     = (const float*)d_in[15];
  const float* bo     = (const float*)d_in[16];
  const float* rf     = (const float*)d_in[17];
  const float* ln1_g  = (const float*)d_in[18];
  const float* ln1_b  = (const float*)d_in[19];
  const float* ln2_g  = (const float*)d_in[20];
  const float* ln2_b  = (const float*)d_in[21];
  const float* ff_w1  = (const float*)d_in[22];
  const float* ff_b1  = (const float*)d_in[23];
  const float* ff_w2  = (const float*)d_in[24];
  const float* ff_b2  = (const float*)d_in[25];
  const float* dec_w1 = (const float*)d_in[26];
  const float* dec_b1 = (const float*)d_in[27];
  const float* bn3_g  = (const float*)d_in[28];
  const float* bn3_b  = (const float*)d_in[29];
  const float* dec_w2 = (const float*)d_in[30];
  const float* dec_b2 = (const float*)d_in[31];

  char* W = (char*)d_ws;

  // ---- fixed region (weights, ~12.2 MB; reserve 16 MB) ----
  bf16_t* weff = (bf16_t*)(W + 0);                     // 4*1280*256*2 = 2,621,440
  float*  beff = (float*)(W + 2621440);                // 20,480
  bf16_t* wot  = (bf16_t*)(W + 2641920);               // 524,288
  bf16_t* w1t  = (bf16_t*)(W + 3166208);               // 2,097,152
  bf16_t* w2t  = (bf16_t*)(W + 5263360);               // 2,097,152
  bf16_t* c2t  = (bf16_t*)(W + 7360512);               // 327,680
  bf16_t* d1t  = (bf16_t*)(W + 7688192);               // 327,680
  float*  pe   = (float*)(W + 8015872);                // 4,194,304
  float*  sc1  = (float*)(W + 12210176);
  float*  sb1  = (float*)(W + 12211200);
  float*  sc2  = (float*)(W + 12212224);
  float*  sb2  = (float*)(W + 12213248);
  float*  sc3  = (float*)(W + 12214272);
  float*  sb3  = (float*)(W + 12215296);
  const size_t FIXED_END = 16777216;

  // ---- pick batch chunk Bc so workspace fits ws_size ----
  const size_t PER_B = 17385472;
  int Bc = 32;
  while (Bc > 1 && FIXED_END + (size_t)Bc * PER_B > ws_size) Bc >>= 1;

  char* P = W + FIXED_END;
  float*  h     = (float*)P;
  bf16_t* xa    = (bf16_t*)(P + (size_t)Bc * 4194304);
  bf16_t* ao    = xa;  // xa dead after fused qkv gemm; ao dead before ln2
  char*   big   = P + (size_t)Bc * (4194304 + 2097152);
  bf16_t* qpkpv = (bf16_t*)big;
  bf16_t* f1    = (bf16_t*)big;                               // after qpkpv dead
  bf16_t* h1p   = (bf16_t*)big;                               // pre-loop
  bf16_t* hpad  = (bf16_t*)big;                               // post-loop
  bf16_t* hdp   = (bf16_t*)(big + (size_t)Bc * 4100 * 256 * 2);
  float*  pkv   = (float*)(big + (size_t)Bc * 10485760);
  float*  pks   = (float*)((char*)pkv + (size_t)Bc * 524288);
  float*  kvb   = (float*)((char*)pks + (size_t)Bc * 16384);
  float*  ksum  = (float*)((char*)kvb + (size_t)Bc * 65536);

  // ---- weight prep (once) ----
  prep_weff<<<5120, 256, 0, stream>>>(wq, wk, wv, bq, bk, bv, rf, weff, beff);
  prep_cast_t<<<1024, 256, 0, stream>>>(wo, wot, 256, 256);
  prep_cast_t<<<4096, 256, 0, stream>>>(ff_w1, w1t, 256, 1024);
  prep_cast_t<<<4096, 256, 0, stream>>>(ff_w2, w2t, 1024, 256);
  prep_conv_t<<<640, 256, 0, stream>>>(emb_w2, c2t, 128, 5);
  prep_conv_t<<<640, 256, 0, stream>>>(dec_w1, d1t, 256, 5);
  prep_bn<<<1, 256, 0, stream>>>(bn1_g, bn1_b, emb_b1, bn2_g, bn2_b, emb_b2,
                                 bn3_g, bn3_b, dec_b1, sc1, sb1, sc2, sb2, sc3, sb3);
  pe_fill<<<4096, 256, 0, stream>>>(pe);

  for (int c0 = 0; c0 < 32; c0 += Bc) {
    const float* xc = x + (size_t)c0 * 4096;

    // ---- embedding ----
    hipMemsetAsync(h1p, 0, (size_t)Bc * 4100 * 128 * 2, stream);
    conv1_kernel<<<Bc * 64, 256, 0, stream>>>(xc, emb_w1, sc1, sb1, h1p);
    gemm_bf16<3><<<dim3(Bc * 32, 2), 256, 0, stream>>>(
        h1p, c2t, h, sb2, sc2, nullptr, pe,
        640, 128, 4100L * 128, 4096, 256, 256, 4096L * 256, 0);

    // ---- transformer layers ----
    for (int l = 0; l < 4; l++) {
      ln_kernel<<<Bc * 1024, 256, 0, stream>>>(h, ln1_g + l * 256, ln1_b + l * 256, xa);
      gemm_bf16<5><<<dim3(Bc * 32, 10), 256, 0, stream>>>(
          xa, weff + (long)l * 327680, qpkpv, beff + l * 1280, nullptr, nullptr, nullptr,
          256, 256, 4096L * 256, 4096, 1280, 1280, 4096L * 1280, 0);
      kv_partial<<<Bc * 64, 256, 0, stream>>>(qpkpv, pkv, pks);
      kv_reduce<<<Bc * 64, 256, 0, stream>>>(pkv, pks, kvb, ksum, Bc * 8);
      combine_mfma<<<Bc * 256, 256, 0, stream>>>(qpkpv, kvb, ksum, ao);
      gemm_bf16<1><<<dim3(Bc * 32, 2), 256, 0, stream>>>(
          ao, wot + (long)l * 65536, h, bo + l * 256, nullptr, h, nullptr,
          256, 256, 4096L * 256, 4096, 256, 256, 4096L * 256, 0);
      ln_kernel<<<Bc * 1024, 256, 0, stream>>>(h, ln2_g + l * 256, ln2_b + l * 256, xa);
      gemm_bf16<2><<<dim3(Bc * 32, 8), 256, 0, stream>>>(
          xa, w1t + (long)l * 262144, f1, ff_b1 + l * 1024, nullptr, nullptr, nullptr,
          256, 256, 4096L * 256, 4096, 1024, 1024, 4096L * 1024, 0);
      gemm_bf16<1><<<dim3(Bc * 32, 2), 256, 0, stream>>>(
          f1, w2t + (long)l * 262144, h, ff_b2 + l * 256, nullptr, h, nullptr,
          1024, 1024, 4096L * 1024, 4096, 256, 256, 4096L * 256, 0);
    }

    // ---- decoder ----
    hipMemsetAsync(hpad, 0, (size_t)Bc * 4100 * 256 * 2, stream);
    cast_pad<<<Bc * 512, 256, 0, stream>>>(h, hpad);
    hipMemsetAsync(hdp, 0, (size_t)Bc * 4098 * 128 * 2, stream);
    gemm_bf16<4><<<dim3(Bc * 32, 1), 256, 0, stream>>>(
        hpad, d1t, hdp, sb3, sc3, nullptr, nullptr,
        1280, 256, 4100L * 256, 4096, 128, 128, 4098L * 128, 1);
    conv_final<<<Bc * 16, 256, 0, stream>>>(hdp, dec_w2, dec_b2,
                                            (float*)d_out + (size_t)c0 * 4096);
  }
}

// Round 4
// 5005.796 us; speedup vs baseline: 1.3652x; 1.3652x over previous
//
#include <hip/hip_runtime.h>
#include <hip/hip_bf16.h>
#include <math.h>

// ============================================================================
// PPGPeakPerformer forward on MI355X (gfx950)
// B=32 S=4096 D=256 DH=128 H=8 HD=32 F=64 L=4
// Batch-chunked (runtime Bc chosen to fit ws_size). Fused q/k RF projection:
// softplus((x@Wq+b)@rf) == softplus(x@(Wq@rf)+(b@rf)) -> one N=1280 GEMM.
// bf16 MFMA GEMMs: 128x128 tile, BK=64, double-buffered LDS (2-phase
// prefetch pipeline), XOR-swizzled LDS via pre-swizzled global source +
// global_load_lds dwordx4 direct staging, weights [N][K].
// Convs as im2col GEMMs; deterministic chunked kv reduction; combine via
// MFMA with denom column. Fast HW transcendentals for softplus/sigmoid.
// ============================================================================

typedef __bf16 bf16_t;
typedef __bf16 bf16x8 __attribute__((ext_vector_type(8)));
typedef __bf16 bf16x4 __attribute__((ext_vector_type(4)));
typedef float  f32x4  __attribute__((ext_vector_type(4)));

#define DEV __device__ __forceinline__

DEV float geluf(float v) { return 0.5f * v * (1.f + erff(v * 0.70710678118654752440f)); }
// softplus(v) = max(v,0) + log(1+exp(-|v|))  (exact identity, HW exp/log)
DEV float softplusf(float v) {
  float e = __expf(-fabsf(v));
  return fmaxf(v, 0.f) + __logf(1.f + e);
}

// Direct global->LDS 16B staging (no VGPR round-trip). LDS dest must be
// wave-uniform base; HW writes base + lane*16 (rule 21: linear dest).
DEV void gload16(const bf16_t* g, bf16_t* l) {
  __builtin_amdgcn_global_load_lds(
      (const __attribute__((address_space(1))) void*)g,
      (__attribute__((address_space(3))) void*)l, 16, 0, 0);
}

// ---------------------------------------------------------------------------
// GEMM: C[m,n] = sum_k A[m,k]*Bt[n,k].  A bf16 (batched rows), Bt bf16 [N][K].
// Row r -> b = r/rpb, s = r%rpb; A elem = A + b*a_bstride + s*lda + k.
// C index  = b*c_bstride + (s + c_roff)*ldc + col.
// EPI: 1 = +bias +resid -> fp32   (O-proj, FF2; resid==Cout, elementwise safe)
//      2 = gelu(+bias) -> bf16    (FF1)
//      3 = gelu(scale*x+bias)+pe -> fp32  (embed conv2)
//      4 = gelu(scale*x+bias) -> bf16     (decoder conv1)
//      5 = col<1024 ? softplus(+bias) : (+bias) -> bf16   (fused qp/kp/v)
// Staging: wave w owns rows [32w,32w+32). Per 8-row group the lane's global
// source slot is XORed by its row-in-group, so LDS ends up XOR-swizzled
// (byte ^= (r&7)<<4) while the gload_lds dest stays linear.
// Pipeline: double-buffered LDS; prefetch tile t+1 issued BEFORE computing
// tile t; single __syncthreads (drains vmcnt) per tile.
// ---------------------------------------------------------------------------
template <int EPI>
__global__ __launch_bounds__(256, 2)
void gemm_bf16(const bf16_t* __restrict__ A, const bf16_t* __restrict__ Bt,
               void* Cout, const float* __restrict__ bias,
               const float* __restrict__ scale, const float* resid,
               const float* __restrict__ pe,
               int K, int lda, long a_bstride, int rpb,
               int N, int ldc, long c_bstride, int c_roff)
{
  __shared__ bf16_t As[2][128 * 64];
  __shared__ bf16_t Bs[2][128 * 64];
  const int t = threadIdx.x;
  const int lane = t & 63;
  const int w = t >> 6;
  const int wm = w >> 1, wn = w & 1;
  const long m0 = (long)blockIdx.x * 128;
  const int n0 = blockIdx.y * 128;
  const int b = (int)(m0 / rpb);
  const int s_base = (int)(m0 % rpb);
  const bf16_t* Ab = A + (long)b * a_bstride + (long)s_base * lda;
  const bf16_t* Bb = Bt + (long)n0 * K;

  // staging source bases (pre-swizzled slot)
  const int sr = lane >> 3;                 // row-in-8-group == r&7
  const int soff = ((lane & 7) ^ sr) * 8;   // element offset within 64-elem row
  const bf16_t* aSrc = Ab + (long)(w * 32 + sr) * lda + soff;
  const bf16_t* bSrc = Bb + (long)(w * 32 + sr) * K + soff;
  const int dstoff = w * 32 * 64;

  f32x4 acc[4][4];
#pragma unroll
  for (int i = 0; i < 4; i++)
#pragma unroll
    for (int j = 0; j < 4; j++) acc[i][j] = (f32x4){0.f, 0.f, 0.f, 0.f};

  const int NT = K >> 6;
  // prologue: stage tile 0 into buffer 0
#pragma unroll
  for (int i = 0; i < 4; i++) {
    gload16(aSrc + (long)(i * 8) * lda, &As[0][dstoff + i * 8 * 64]);
    gload16(bSrc + (long)(i * 8) * K,  &Bs[0][dstoff + i * 8 * 64]);
  }
  __syncthreads();

  int cur = 0;
  for (int tt = 0; tt < NT; ++tt) {
    // issue prefetch of next tile into the other buffer (before compute)
    if (tt + 1 < NT) {
      const int k0 = (tt + 1) << 6;
#pragma unroll
      for (int i = 0; i < 4; i++) {
        gload16(aSrc + k0 + (long)(i * 8) * lda, &As[cur ^ 1][dstoff + i * 8 * 64]);
        gload16(bSrc + k0 + (long)(i * 8) * K,  &Bs[cur ^ 1][dstoff + i * 8 * 64]);
      }
    }
    const bf16_t* Ac = As[cur];
    const bf16_t* Bc = Bs[cur];
#pragma unroll
    for (int kt = 0; kt < 2; kt++) {
      const int kb = kt * 64 + (lane >> 4) * 16;
      bf16x8 af[4], bfr[4];
#pragma unroll
      for (int i = 0; i < 4; i++) {
        int rA = wm * 64 + i * 16 + (lane & 15);
        af[i] = *(const bf16x8*)((const char*)Ac + rA * 128 + (kb ^ ((rA & 7) << 4)));
        int rB = wn * 64 + i * 16 + (lane & 15);
        bfr[i] = *(const bf16x8*)((const char*)Bc + rB * 128 + (kb ^ ((rB & 7) << 4)));
      }
#pragma unroll
      for (int mi = 0; mi < 4; mi++)
#pragma unroll
        for (int ni = 0; ni < 4; ni++)
          acc[mi][ni] = __builtin_amdgcn_mfma_f32_16x16x32_bf16(af[mi], bfr[ni], acc[mi][ni], 0, 0, 0);
    }
    __syncthreads();  // drains vmcnt: prefetched tile visible; cur free for reuse
    cur ^= 1;
  }

  const int colbase = n0 + wn * 64 + (lane & 15);
  float bias_r[4], scale_r[4];
#pragma unroll
  for (int ni = 0; ni < 4; ni++) {
    int col = colbase + ni * 16;
    bias_r[ni] = bias[col];
    scale_r[ni] = (EPI == 3 || EPI == 4) ? scale[col] : 0.f;
  }
#pragma unroll
  for (int mi = 0; mi < 4; mi++) {
#pragma unroll
    for (int j = 0; j < 4; j++) {
      int row = wm * 64 + mi * 16 + ((lane >> 4) << 2) + j;
      long s = s_base + row;
      long cro = (long)b * c_bstride + (s + c_roff) * (long)ldc;
#pragma unroll
      for (int ni = 0; ni < 4; ni++) {
        int col = colbase + ni * 16;
        float v = acc[mi][ni][j];
        if constexpr (EPI == 1) {
          v += bias_r[ni] + resid[cro + col];
          ((float*)Cout)[cro + col] = v;
        } else if constexpr (EPI == 2) {
          v = geluf(v + bias_r[ni]);
          ((bf16_t*)Cout)[cro + col] = (bf16_t)v;
        } else if constexpr (EPI == 3) {
          v = geluf(v * scale_r[ni] + bias_r[ni]) + pe[s * 256 + col];
          ((float*)Cout)[cro + col] = v;
        } else if constexpr (EPI == 4) {
          v = geluf(v * scale_r[ni] + bias_r[ni]);
          ((bf16_t*)Cout)[cro + col] = (bf16_t)v;
        } else {  // 5
          v += bias_r[ni];
          if (col < 1024) v = softplusf(v);
          ((bf16_t*)Cout)[cro + col] = (bf16_t)v;
        }
      }
    }
  }
}

// ---------------------------------------------------------------------------
// LayerNorm over D=256, fp32 in -> bf16 out. 4 rows/block (1 wave per row).
// ---------------------------------------------------------------------------
__global__ __launch_bounds__(256)
void ln_kernel(const float* __restrict__ h, const float* __restrict__ g,
               const float* __restrict__ bta, bf16_t* __restrict__ out)
{
  int t = threadIdx.x;
  int lane = t & 63;
  long row = (long)blockIdx.x * 4 + (t >> 6);
  const float* hp = h + row * 256 + lane * 4;
  float4 v = *(const float4*)hp;
  float s = v.x + v.y + v.z + v.w;
  float q = v.x * v.x + v.y * v.y + v.z * v.z + v.w * v.w;
#pragma unroll
  for (int m = 32; m >= 1; m >>= 1) {
    s += __shfl_xor(s, m);
    q += __shfl_xor(q, m);
  }
  float mean = s * 0.00390625f;
  float var = q * 0.00390625f - mean * mean;
  float rstd = rsqrtf(var + 1e-5f);
  int c = lane * 4;
  float4 gv = *(const float4*)(g + c);
  float4 bv = *(const float4*)(bta + c);
  bf16x4 o;
  o[0] = (bf16_t)((v.x - mean) * rstd * gv.x + bv.x);
  o[1] = (bf16_t)((v.y - mean) * rstd * gv.y + bv.y);
  o[2] = (bf16_t)((v.z - mean) * rstd * gv.z + bv.z);
  o[3] = (bf16_t)((v.w - mean) * rstd * gv.w + bv.w);
  *(bf16x4*)(out + row * 256 + c) = o;
}

// ---------------------------------------------------------------------------
// Embedding conv1: x[Bc,S] -> gelu(bn(conv1d k=7 pad=3)) -> h1p[Bc,S+4,128]
// ---------------------------------------------------------------------------
__global__ __launch_bounds__(256)
void conv1_kernel(const float* __restrict__ x, const float* __restrict__ w1,
                  const float* __restrict__ sc, const float* __restrict__ sb,
                  bf16_t* __restrict__ h1p)
{
  int b = blockIdx.x >> 6;
  int s0 = (blockIdx.x & 63) << 6;
  __shared__ float xs[70];
  __shared__ float ws[896];
  int t = threadIdx.x;
  if (t < 70) {
    int s = s0 + t - 3;
    xs[t] = (s >= 0 && s < 4096) ? x[(long)b * 4096 + s] : 0.f;
  }
  for (int i = t; i < 896; i += 256) ws[i] = w1[i];
  __syncthreads();
  int c = t & 127, so = t >> 7;
  float wr[7];
#pragma unroll
  for (int k = 0; k < 7; k++) wr[k] = ws[c * 7 + k];
  float scl = sc[c], sbv = sb[c];
  for (int p = 0; p < 32; p++) {
    int sl = p * 2 + so;
    float a = 0.f;
#pragma unroll
    for (int k = 0; k < 7; k++) a += xs[sl + k] * wr[k];
    a = geluf(a * scl + sbv);
    h1p[((long)b * 4100 + s0 + sl + 2) * 128 + c] = (bf16_t)a;
  }
}

// ---------------------------------------------------------------------------
// kv partial: per (b,h,chunk of 512 s): acc[f][d] += kp[s,f]*v[s,d]; +ksum.
// kp/v read from fused qpkpv rows (stride 1280: [qp 0..511 | kp 512..1023 |
// v 1024..1279]). Deterministic fixed partial order.
// ---------------------------------------------------------------------------
__global__ __launch_bounds__(256)
void kv_partial(const bf16_t* __restrict__ qpkpv,
                float* __restrict__ pkv, float* __restrict__ pks)
{
  int bh = blockIdx.x >> 3, ch = blockIdx.x & 7;
  int b = bh >> 3, hh = bh & 7;
  int s0 = ch * 512;
  __shared__ float kps[32 * 64];
  __shared__ float vs[32 * 32];
  int t = threadIdx.x;
  int f = t & 63, dg = t >> 6;
  float acc[8] = {0.f, 0.f, 0.f, 0.f, 0.f, 0.f, 0.f, 0.f};
  float ks = 0.f;
  const int row = t >> 3, slot8 = (t & 7) * 8, slot4 = (t & 7) * 4;
  for (int sb = 0; sb < 512; sb += 32) {
    __syncthreads();
    {
      const bf16_t* rowp = qpkpv + ((long)b * 4096 + s0 + sb + row) * 1280;
      bf16x8 k8 = *(const bf16x8*)(rowp + 512 + hh * 64 + slot8);
#pragma unroll
      for (int j = 0; j < 8; j++) kps[row * 64 + slot8 + j] = (float)k8[j];
      bf16x4 v4 = *(const bf16x4*)(rowp + 1024 + hh * 32 + slot4);
#pragma unroll
      for (int j = 0; j < 4; j++) vs[row * 32 + slot4 + j] = (float)v4[j];
    }
    __syncthreads();
#pragma unroll 4
    for (int s = 0; s < 32; s++) {
      float kval = kps[s * 64 + f];
      float4 v0 = *(const float4*)&vs[s * 32 + dg * 8];
      float4 v1 = *(const float4*)&vs[s * 32 + dg * 8 + 4];
      acc[0] += kval * v0.x; acc[1] += kval * v0.y;
      acc[2] += kval * v0.z; acc[3] += kval * v0.w;
      acc[4] += kval * v1.x; acc[5] += kval * v1.y;
      acc[6] += kval * v1.z; acc[7] += kval * v1.w;
      ks += kval;
    }
  }
  long o = (long)blockIdx.x * 2048 + f * 32 + dg * 8;
#pragma unroll
  for (int j = 0; j < 8; j++) pkv[o + j] = acc[j];
  if (dg == 0) pks[blockIdx.x * 64 + f] = ks;
}

__global__ __launch_bounds__(256)
void kv_reduce(const float* __restrict__ pkv, const float* __restrict__ pks,
               float* __restrict__ kv, float* __restrict__ ksum, int nbh)
{
  long idx = (long)blockIdx.x * 256 + threadIdx.x;  // nbh*2048
  {
    int bh = (int)(idx >> 11), fd = (int)(idx & 2047);
    float s = 0.f;
#pragma unroll
    for (int ch = 0; ch < 8; ch++) s += pkv[((long)(bh * 8 + ch)) * 2048 + fd];
    kv[idx] = s;
  }
  if (idx < (long)nbh * 64) {
    int bh = (int)(idx >> 6), f = (int)(idx & 63);
    float s = 0.f;
#pragma unroll
    for (int ch = 0; ch < 8; ch++) s += pks[(bh * 8 + ch) * 64 + f];
    ksum[idx] = s;
  }
}

// ---------------------------------------------------------------------------
// combine: ao[s, h*32+d] = (qp[s,:] @ kv[:,d]) / (qp[s,:]@ksum + 1e-8)
// MFMA with B = [kv^T | ksum | 0pad] (48 cols), denom broadcast via shfl.
// ---------------------------------------------------------------------------
__global__ __launch_bounds__(256, 2)
void combine_mfma(const bf16_t* __restrict__ qpkpv, const float* __restrict__ kv,
                  const float* __restrict__ ksum, bf16_t* __restrict__ ao)
{
  int bh = blockIdx.x >> 5;
  int s0 = (blockIdx.x & 31) << 7;
  int b = bh >> 3, hh = bh & 7;
  __shared__ bf16_t A_s[128 * 72];
  __shared__ bf16_t B_s[48 * 72];
  int t = threadIdx.x;
  for (int g = t; g < 1024; g += 256) {
    int row = g >> 3, slot = (g & 7) * 8;
    *(bf16x8*)&A_s[row * 72 + slot] =
        *(const bf16x8*)(qpkpv + ((long)b * 4096 + s0 + row) * 1280 + hh * 64 + slot);
  }
  for (int i = t; i < 2048; i += 256) {
    int f = i >> 5, d = i & 31;
    B_s[d * 72 + f] = (bf16_t)kv[(long)bh * 2048 + i];
  }
  if (t < 64) B_s[32 * 72 + t] = (bf16_t)ksum[bh * 64 + t];
  for (int i = t; i < 960; i += 256) {
    int n = 33 + (i >> 6), f = i & 63;
    B_s[n * 72 + f] = (bf16_t)0.f;
  }
  __syncthreads();
  int lane = t & 63, w = t >> 6;
  f32x4 acc[2][3];
#pragma unroll
  for (int i = 0; i < 2; i++)
#pragma unroll
    for (int j = 0; j < 3; j++) acc[i][j] = (f32x4){0.f, 0.f, 0.f, 0.f};
#pragma unroll
  for (int kt = 0; kt < 2; kt++) {
    int ko = kt * 32 + (lane >> 4) * 8;
    bf16x8 a[2], bb[3];
#pragma unroll
    for (int i = 0; i < 2; i++)
      a[i] = *(const bf16x8*)&A_s[(w * 32 + i * 16 + (lane & 15)) * 72 + ko];
#pragma unroll
    for (int i = 0; i < 3; i++)
      bb[i] = *(const bf16x8*)&B_s[(i * 16 + (lane & 15)) * 72 + ko];
#pragma unroll
    for (int mi = 0; mi < 2; mi++)
#pragma unroll
      for (int ni = 0; ni < 3; ni++)
        acc[mi][ni] = __builtin_amdgcn_mfma_f32_16x16x32_bf16(a[mi], bb[ni], acc[mi][ni], 0, 0, 0);
  }
  long sbase = (long)b * 4096 + s0;
#pragma unroll
  for (int mi = 0; mi < 2; mi++)
#pragma unroll
    for (int j = 0; j < 4; j++) {
      int r = w * 32 + mi * 16 + ((lane >> 4) << 2) + j;
      float den = __shfl(acc[mi][2][j], (lane & 48)) + 1e-8f;
#pragma unroll
      for (int ni = 0; ni < 2; ni++) {
        int d = ni * 16 + (lane & 15);
        ao[(sbase + r) * 256 + hh * 32 + d] = (bf16_t)(acc[mi][ni][j] / den);
      }
    }
}

// ---------------------------------------------------------------------------
// h fp32 -> h_padded bf16 [Bc, S+4, 256] (rows offset +2)
// ---------------------------------------------------------------------------
__global__ __launch_bounds__(256)
void cast_pad(const float* __restrict__ h, bf16_t* __restrict__ hp)
{
  long i8 = ((long)blockIdx.x * 256 + threadIdx.x) * 8;
  long r = i8 >> 8;
  int c = (int)(i8 & 255);
  int b = (int)(r >> 12), s = (int)(r & 4095);
  float4 v0 = *(const float4*)(h + i8);
  float4 v1 = *(const float4*)(h + i8 + 4);
  bf16x8 o;
  o[0] = (bf16_t)v0.x; o[1] = (bf16_t)v0.y; o[2] = (bf16_t)v0.z; o[3] = (bf16_t)v0.w;
  o[4] = (bf16_t)v1.x; o[5] = (bf16_t)v1.y; o[6] = (bf16_t)v1.z; o[7] = (bf16_t)v1.w;
  *(bf16x8*)(hp + ((long)b * 4100 + s + 2) * 256 + c) = o;
}

// ---------------------------------------------------------------------------
// Final conv (DH->1, k=3, pad=1) + sigmoid -> out [Bc,S] fp32
// ---------------------------------------------------------------------------
__global__ __launch_bounds__(256)
void conv_final(const bf16_t* __restrict__ hdp, const float* __restrict__ w2,
                const float* __restrict__ b2, float* __restrict__ out)
{
  __shared__ float ws[384];
  int t = threadIdx.x;
  for (int i = t; i < 384; i += 256) ws[i] = w2[i];  // [c][k]
  __syncthreads();
  long idx = (long)blockIdx.x * 256 + t;
  int b = (int)(idx >> 12);
  const bf16_t* base = hdp + ((long)b * 4098 + (idx & 4095)) * 128;
  float a = b2[0];
#pragma unroll
  for (int k = 0; k < 3; k++) {
#pragma unroll
    for (int c8 = 0; c8 < 16; c8++) {
      bf16x8 v = *(const bf16x8*)(base + k * 128 + c8 * 8);
#pragma unroll
      for (int j = 0; j < 8; j++) a += (float)v[j] * ws[(c8 * 8 + j) * 3 + k];
    }
  }
  out[idx] = 1.f / (1.f + __expf(-a));
}

// ---------------------------------------------------------------------------
// Prep kernels (once per launch)
// ---------------------------------------------------------------------------
__global__ __launch_bounds__(256)
void prep_weff(const float* __restrict__ wq, const float* __restrict__ wk,
               const float* __restrict__ wv, const float* __restrict__ bq,
               const float* __restrict__ bk, const float* __restrict__ bv,
               const float* __restrict__ rf, bf16_t* __restrict__ weff,
               float* __restrict__ beff)
{
  long idx = (long)blockIdx.x * 256 + threadIdx.x;  // 4*1280*256
  int d = (int)(idx & 255);
  long r = idx >> 8;
  int n = (int)(r % 1280);
  int l = (int)(r / 1280);
  float val;
  if (n < 1024) {
    int qk = n >> 9;
    int h = (n >> 6) & 7;
    int f = n & 63;
    const float* w = qk ? wk : wq;
    const float* rfh = rf + ((long)(l * 8 + h) * 32) * 64 + f;
    const float* wrow = w + ((long)l * 256 + d) * 256 + h * 32;
    float s = 0.f;
#pragma unroll
    for (int hd = 0; hd < 32; hd++) s += wrow[hd] * rfh[hd * 64];
    val = s;
  } else {
    val = wv[((long)l * 256 + d) * 256 + (n - 1024)];
  }
  weff[idx] = (bf16_t)val;
  if (idx < 4 * 1280) {
    int nn = (int)(idx % 1280);
    int ll = (int)(idx / 1280);
    float bvv;
    if (nn < 1024) {
      int qk = nn >> 9;
      int h = (nn >> 6) & 7;
      int f = nn & 63;
      const float* bsrc = qk ? bk : bq;
      float s = 0.f;
      for (int hd = 0; hd < 32; hd++)
        s += bsrc[ll * 256 + h * 32 + hd] * rf[((long)(ll * 8 + h) * 32 + hd) * 64 + f];
      bvv = s;
    } else {
      bvv = bv[ll * 256 + (nn - 1024)];
    }
    beff[idx] = bvv;
  }
}

__global__ __launch_bounds__(256)
void prep_cast_t(const float* __restrict__ src, bf16_t* __restrict__ dst, int K, int N)
{
  long idx = (long)blockIdx.x * 256 + threadIdx.x;  // nmats*N*K
  int k = (int)(idx % K);
  long r = idx / K;
  int n = (int)(r % N);
  int l = (int)(r / N);
  dst[idx] = (bf16_t)src[((long)l * K + k) * N + n];
}

__global__ __launch_bounds__(256)
void prep_conv_t(const float* __restrict__ w, bf16_t* __restrict__ dst, int C, int KW)
{
  long idx = (long)blockIdx.x * 256 + threadIdx.x;  // O*C*KW
  int ckw = C * KW;
  int kk = (int)(idx % ckw);
  int o = (int)(idx / ckw);
  int kw = kk / C, c = kk % C;
  dst[idx] = (bf16_t)w[((long)o * C + c) * KW + kw];
}

__global__ __launch_bounds__(256)
void prep_bn(const float* g1, const float* b1, const float* cb1,
             const float* g2, const float* b2, const float* cb2,
             const float* g3, const float* b3, const float* cb3,
             float* sc1, float* sb1, float* sc2, float* sb2,
             float* sc3, float* sb3)
{
  int t = threadIdx.x;
  const float r = rsqrtf(1.f + 1e-5f);
  if (t < 128) { float s = g1[t] * r; sc1[t] = s; sb1[t] = cb1[t] * s + b1[t]; }
  if (t < 256) { float s = g2[t] * r; sc2[t] = s; sb2[t] = cb2[t] * s + b2[t]; }
  if (t < 128) { float s = g3[t] * r; sc3[t] = s; sb3[t] = cb3[t] * s + b3[t]; }
}

__global__ __launch_bounds__(256)
void pe_fill(float* __restrict__ pe)
{
  long idx = (long)blockIdx.x * 256 + threadIdx.x;  // 4096*256
  int dcol = (int)(idx & 255);
  int s = (int)(idx >> 8);
  int i2 = dcol >> 1;
  float freq = expf(-9.210340371976184f * (float)(2 * i2) / 256.f);
  float a = (float)s * freq;
  pe[idx] = (dcol & 1) ? cosf(a) : sinf(a);
}

// ---------------------------------------------------------------------------
extern "C" void kernel_launch(void* const* d_in, const int* in_sizes, int n_in,
                              void* d_out, int out_size, void* d_ws, size_t ws_size,
                              hipStream_t stream)
{
  (void)in_sizes; (void)n_in; (void)out_size;
  const float* x      = (const float*)d_in[0];
  const float* emb_w1 = (const float*)d_in[1];
  const float* emb_b1 = (const float*)d_in[2];
  const float* bn1_g  = (const float*)d_in[3];
  const float* bn1_b  = (const float*)d_in[4];
  const float* emb_w2 = (const float*)d_in[5];
  const float* emb_b2 = (const float*)d_in[6];
  const float* bn2_g  = (const float*)d_in[7];
  const float* bn2_b  = (const float*)d_in[8];
  const float* wq     = (const float*)d_in[9];
  const float* bq     = (const float*)d_in[10];
  const float* wk     = (const float*)d_in[11];
  const float* bk     = (const float*)d_in[12];
  const float* wv     = (const float*)d_in[13];
  const float* bv     = (const float*)d_in[14];
  const float* wo     = (const float*)d_in[15];
  const float* bo     = (const float*)d_in[16];
  const float* rf     = (const float*)d_in[17];
  const float* ln1_g  = (const float*)d_in[18];
  const float* ln1_b  = (const float*)d_in[19];
  const float* ln2_g  = (const float*)d_in[20];
  const float* ln2_b  = (const float*)d_in[21];
  const float* ff_w1  = (const float*)d_in[22];
  const float* ff_b1  = (const float*)d_in[23];
  const float* ff_w2  = (const float*)d_in[24];
  const float* ff_b2  = (const float*)d_in[25];
  const float* dec_w1 = (const float*)d_in[26];
  const float* dec_b1 = (const float*)d_in[27];
  const float* bn3_g  = (const float*)d_in[28];
  const float* bn3_b  = (const float*)d_in[29];
  const float* dec_w2 = (const float*)d_in[30];
  const float* dec_b2 = (const float*)d_in[31];

  char* W = (char*)d_ws;

  // ---- fixed region (weights, ~12.2 MB; reserve 16 MB) ----
  bf16_t* weff = (bf16_t*)(W + 0);                     // 4*1280*256*2 = 2,621,440
  float*  beff = (float*)(W + 2621440);                // 20,480
  bf16_t* wot  = (bf16_t*)(W + 2641920);               // 524,288
  bf16_t* w1t  = (bf16_t*)(W + 3166208);               // 2,097,152
  bf16_t* w2t  = (bf16_t*)(W + 5263360);               // 2,097,152
  bf16_t* c2t  = (bf16_t*)(W + 7360512);               // 327,680
  bf16_t* d1t  = (bf16_t*)(W + 7688192);               // 327,680
  float*  pe   = (float*)(W + 8015872);                // 4,194,304
  float*  sc1  = (float*)(W + 12210176);
  float*  sb1  = (float*)(W + 12211200);
  float*  sc2  = (float*)(W + 12212224);
  float*  sb2  = (float*)(W + 12213248);
  float*  sc3  = (float*)(W + 12214272);
  float*  sb3  = (float*)(W + 12215296);
  const size_t FIXED_END = 16777216;

  // ---- pick batch chunk Bc so workspace fits ws_size ----
  const size_t PER_B = 17385472;
  int Bc = 32;
  while (Bc > 1 && FIXED_END + (size_t)Bc * PER_B > ws_size) Bc >>= 1;

  char* P = W + FIXED_END;
  float*  h     = (float*)P;
  bf16_t* xa    = (bf16_t*)(P + (size_t)Bc * 4194304);
  bf16_t* ao    = xa;  // xa dead after fused qkv gemm; ao dead before ln2
  char*   big   = P + (size_t)Bc * (4194304 + 2097152);
  bf16_t* qpkpv = (bf16_t*)big;
  bf16_t* f1    = (bf16_t*)big;                               // after qpkpv dead
  bf16_t* h1p   = (bf16_t*)big;                               // pre-loop
  bf16_t* hpad  = (bf16_t*)big;                               // post-loop
  bf16_t* hdp   = (bf16_t*)(big + (size_t)Bc * 4100 * 256 * 2);
  float*  pkv   = (float*)(big + (size_t)Bc * 10485760);
  float*  pks   = (float*)((char*)pkv + (size_t)Bc * 524288);
  float*  kvb   = (float*)((char*)pks + (size_t)Bc * 16384);
  float*  ksum  = (float*)((char*)kvb + (size_t)Bc * 65536);

  // ---- weight prep (once) ----
  prep_weff<<<5120, 256, 0, stream>>>(wq, wk, wv, bq, bk, bv, rf, weff, beff);
  prep_cast_t<<<1024, 256, 0, stream>>>(wo, wot, 256, 256);
  prep_cast_t<<<4096, 256, 0, stream>>>(ff_w1, w1t, 256, 1024);
  prep_cast_t<<<4096, 256, 0, stream>>>(ff_w2, w2t, 1024, 256);
  prep_conv_t<<<640, 256, 0, stream>>>(emb_w2, c2t, 128, 5);
  prep_conv_t<<<640, 256, 0, stream>>>(dec_w1, d1t, 256, 5);
  prep_bn<<<1, 256, 0, stream>>>(bn1_g, bn1_b, emb_b1, bn2_g, bn2_b, emb_b2,
                                 bn3_g, bn3_b, dec_b1, sc1, sb1, sc2, sb2, sc3, sb3);
  pe_fill<<<4096, 256, 0, stream>>>(pe);

  for (int c0 = 0; c0 < 32; c0 += Bc) {
    const float* xc = x + (size_t)c0 * 4096;

    // ---- embedding ----
    hipMemsetAsync(h1p, 0, (size_t)Bc * 4100 * 128 * 2, stream);
    conv1_kernel<<<Bc * 64, 256, 0, stream>>>(xc, emb_w1, sc1, sb1, h1p);
    gemm_bf16<3><<<dim3(Bc * 32, 2), 256, 0, stream>>>(
        h1p, c2t, h, sb2, sc2, nullptr, pe,
        640, 128, 4100L * 128, 4096, 256, 256, 4096L * 256, 0);

    // ---- transformer layers ----
    for (int l = 0; l < 4; l++) {
      ln_kernel<<<Bc * 1024, 256, 0, stream>>>(h, ln1_g + l * 256, ln1_b + l * 256, xa);
      gemm_bf16<5><<<dim3(Bc * 32, 10), 256, 0, stream>>>(
          xa, weff + (long)l * 327680, qpkpv, beff + l * 1280, nullptr, nullptr, nullptr,
          256, 256, 4096L * 256, 4096, 1280, 1280, 4096L * 1280, 0);
      kv_partial<<<Bc * 64, 256, 0, stream>>>(qpkpv, pkv, pks);
      kv_reduce<<<Bc * 64, 256, 0, stream>>>(pkv, pks, kvb, ksum, Bc * 8);
      combine_mfma<<<Bc * 256, 256, 0, stream>>>(qpkpv, kvb, ksum, ao);
      gemm_bf16<1><<<dim3(Bc * 32, 2), 256, 0, stream>>>(
          ao, wot + (long)l * 65536, h, bo + l * 256, nullptr, h, nullptr,
          256, 256, 4096L * 256, 4096, 256, 256, 4096L * 256, 0);
      ln_kernel<<<Bc * 1024, 256, 0, stream>>>(h, ln2_g + l * 256, ln2_b + l * 256, xa);
      gemm_bf16<2><<<dim3(Bc * 32, 8), 256, 0, stream>>>(
          xa, w1t + (long)l * 262144, f1, ff_b1 + l * 1024, nullptr, nullptr, nullptr,
          256, 256, 4096L * 256, 4096, 1024, 1024, 4096L * 1024, 0);
      gemm_bf16<1><<<dim3(Bc * 32, 2), 256, 0, stream>>>(
          f1, w2t + (long)l * 262144, h, ff_b2 + l * 256, nullptr, h, nullptr,
          1024, 1024, 4096L * 1024, 4096, 256, 256, 4096L * 256, 0);
    }

    // ---- decoder ----
    hipMemsetAsync(hpad, 0, (size_t)Bc * 4100 * 256 * 2, stream);
    cast_pad<<<Bc * 512, 256, 0, stream>>>(h, hpad);
    hipMemsetAsync(hdp, 0, (size_t)Bc * 4098 * 128 * 2, stream);
    gemm_bf16<4><<<dim3(Bc * 32, 1), 256, 0, stream>>>(
        hpad, d1t, hdp, sb3, sc3, nullptr, nullptr,
        1280, 256, 4100L * 256, 4096, 128, 128, 4098L * 128, 1);
    conv_final<<<Bc * 16, 256, 0, stream>>>(hdp, dec_w2, dec_b2,
                                            (float*)d_out + (size_t)c0 * 4096);
  }
}

// Round 5
// 4484.130 us; speedup vs baseline: 1.5240x; 1.1163x over previous
//
#include <hip/hip_runtime.h>
#include <hip/hip_bf16.h>
#include <math.h>

// ============================================================================
// PPGPeakPerformer forward on MI355X (gfx950)
// B=32 S=4096 D=256 DH=128 H=8 HD=32 F=64 L=4
// GEMM: 128x128 tile, BK=32, TRIPLE-buffered LDS with depth-2 prefetch and
// counted s_waitcnt vmcnt(4) + raw s_barrier (T3+T4). XOR-swizzled LDS via
// pre-swizzled global source + global_load_lds dwordx4. Fast rational erf
// (A&S 7.1.26, err 1.5e-7) for all GELUs. Fused q/k RF projection GEMM.
// ============================================================================

typedef __bf16 bf16_t;
typedef __bf16 bf16x8 __attribute__((ext_vector_type(8)));
typedef __bf16 bf16x4 __attribute__((ext_vector_type(4)));
typedef float  f32x4  __attribute__((ext_vector_type(4)));

#define DEV __device__ __forceinline__

DEV float erf_fast(float x) {
  float ax = fabsf(x);
  float t = __builtin_amdgcn_rcpf(1.f + 0.3275911f * ax);
  float p = t * (0.254829592f + t * (-0.284496736f + t * (1.421413741f +
            t * (-1.453152027f + t * 1.061405429f))));
  float r = 1.f - p * __expf(-ax * ax);
  return copysignf(r, x);
}
DEV float geluf(float v) { return 0.5f * v * (1.f + erf_fast(v * 0.70710678118654752440f)); }
DEV float softplusf(float v) {
  float e = __expf(-fabsf(v));
  return fmaxf(v, 0.f) + __logf(1.f + e);
}

// Direct global->LDS 16B staging. LDS dest is wave-uniform base + lane*16.
DEV void gload16(const bf16_t* g, bf16_t* l) {
  __builtin_amdgcn_global_load_lds(
      (const __attribute__((address_space(1))) void*)g,
      (__attribute__((address_space(3))) void*)l, 16, 0, 0);
}

// ---------------------------------------------------------------------------
// GEMM: C[m,n] = sum_k A[m,k]*Bt[n,k].  A bf16 (batched rows), Bt bf16 [N][K].
// EPI: 1 = +bias +resid -> fp32; 2 = gelu(+bias) -> bf16;
//      3 = gelu(scale*x+bias)+pe -> fp32; 4 = gelu(scale*x+bias) -> bf16;
//      5 = col<1024 ? softplus(+bias) : (+bias) -> bf16
// BK=32 (rows of 64B = 4x16B slots). Swizzle: LDS slot = src_slot ^ (row&3).
// Staged via gload16 with pre-swizzled per-lane source; LDS dest linear.
// Triple buffer: at iter t, buffer t%3 is computed, (t+1)%3 is landing,
// (t+2)%3 is issued after the barrier. vmcnt(4) waits only tile t's 4 loads
// (in-order retirement); loads for t+1 stay in flight across the barrier.
// ---------------------------------------------------------------------------
template <int EPI>
__global__ __launch_bounds__(256, 3)
void gemm_bf16(const bf16_t* __restrict__ A, const bf16_t* __restrict__ Bt,
               void* Cout, const float* __restrict__ bias,
               const float* __restrict__ scale, const float* resid,
               const float* __restrict__ pe,
               int K, int lda, long a_bstride, int rpb,
               int N, int ldc, long c_bstride, int c_roff)
{
  __shared__ bf16_t As[3][128 * 32];
  __shared__ bf16_t Bs[3][128 * 32];
  const int t = threadIdx.x;
  const int lane = t & 63;
  const int w = t >> 6;
  const int wm = w >> 1, wn = w & 1;
  const long m0 = (long)blockIdx.x * 128;
  const int n0 = blockIdx.y * 128;
  const int b = (int)(m0 / rpb);
  const int s_base = (int)(m0 % rpb);
  const bf16_t* Ab = A + (long)b * a_bstride + (long)s_base * lda;
  const bf16_t* Bb = Bt + (long)n0 * K;

  // staging source (pre-swizzled): lane covers row (lane>>2) of a 16-row
  // block, 16B slot ((lane&3) ^ (row&3)).
  const int srow = lane >> 2;
  const int sslot = (lane & 3) ^ (srow & 3);
  const bf16_t* aS = Ab + (long)(w * 32 + srow) * lda + sslot * 8;
  const bf16_t* bS = Bb + (long)(w * 32 + srow) * K + sslot * 8;
  const int dsto = w * 1024;  // 32 rows x 32 elems per wave

#define STAGE(bufidx, kk)                                   \
  {                                                         \
    bf16_t* a_ = &As[bufidx][dsto];                         \
    bf16_t* b_ = &Bs[bufidx][dsto];                         \
    gload16(aS + (kk), a_);                                 \
    gload16(aS + (kk) + 16 * (long)lda, a_ + 512);          \
    gload16(bS + (kk), b_);                                 \
    gload16(bS + (kk) + 16 * (long)K, b_ + 512);            \
  }

  f32x4 acc[4][4];
#pragma unroll
  for (int i = 0; i < 4; i++)
#pragma unroll
    for (int j = 0; j < 4; j++) acc[i][j] = (f32x4){0.f, 0.f, 0.f, 0.f};

  const int NT = K >> 5;
  STAGE(0, 0);
  STAGE(1, 32);

  int cur = 0;
  for (int tt = 0; tt < NT; ++tt) {
    if (tt + 1 < NT) {
      asm volatile("s_waitcnt vmcnt(4)" ::: "memory");
    } else {
      asm volatile("s_waitcnt vmcnt(0)" ::: "memory");
    }
    __builtin_amdgcn_s_barrier();
    __builtin_amdgcn_sched_barrier(0);
    if (tt + 2 < NT) {
      int sb = cur + 2; if (sb >= 3) sb -= 3;
      STAGE(sb, (tt + 2) * 32);
    }
    const bf16_t* Acur = As[cur];
    const bf16_t* Bcur = Bs[cur];
    const int kb = (lane >> 4) * 16;
    bf16x8 af[4], bfr[4];
#pragma unroll
    for (int i = 0; i < 4; i++) {
      int rA = wm * 64 + i * 16 + (lane & 15);
      af[i] = *(const bf16x8*)((const char*)Acur + rA * 64 + (kb ^ ((rA & 3) << 4)));
      int rB = wn * 64 + i * 16 + (lane & 15);
      bfr[i] = *(const bf16x8*)((const char*)Bcur + rB * 64 + (kb ^ ((rB & 3) << 4)));
    }
#pragma unroll
    for (int mi = 0; mi < 4; mi++)
#pragma unroll
      for (int ni = 0; ni < 4; ni++)
        acc[mi][ni] = __builtin_amdgcn_mfma_f32_16x16x32_bf16(af[mi], bfr[ni], acc[mi][ni], 0, 0, 0);
    cur = (cur == 2) ? 0 : cur + 1;
  }
#undef STAGE

  const int colbase = n0 + wn * 64 + (lane & 15);
  float bias_r[4], scale_r[4];
#pragma unroll
  for (int ni = 0; ni < 4; ni++) {
    int col = colbase + ni * 16;
    bias_r[ni] = bias[col];
    scale_r[ni] = (EPI == 3 || EPI == 4) ? scale[col] : 0.f;
  }
#pragma unroll
  for (int mi = 0; mi < 4; mi++) {
#pragma unroll
    for (int j = 0; j < 4; j++) {
      int row = wm * 64 + mi * 16 + ((lane >> 4) << 2) + j;
      long s = s_base + row;
      long cro = (long)b * c_bstride + (s + c_roff) * (long)ldc;
#pragma unroll
      for (int ni = 0; ni < 4; ni++) {
        int col = colbase + ni * 16;
        float v = acc[mi][ni][j];
        if constexpr (EPI == 1) {
          v += bias_r[ni] + resid[cro + col];
          ((float*)Cout)[cro + col] = v;
        } else if constexpr (EPI == 2) {
          v = geluf(v + bias_r[ni]);
          ((bf16_t*)Cout)[cro + col] = (bf16_t)v;
        } else if constexpr (EPI == 3) {
          v = geluf(v * scale_r[ni] + bias_r[ni]) + pe[s * 256 + col];
          ((float*)Cout)[cro + col] = v;
        } else if constexpr (EPI == 4) {
          v = geluf(v * scale_r[ni] + bias_r[ni]);
          ((bf16_t*)Cout)[cro + col] = (bf16_t)v;
        } else {  // 5
          v += bias_r[ni];
          if (col < 1024) v = softplusf(v);
          ((bf16_t*)Cout)[cro + col] = (bf16_t)v;
        }
      }
    }
  }
}

// ---------------------------------------------------------------------------
// LayerNorm over D=256, fp32 in -> bf16 out. 4 rows/block (1 wave per row).
// ---------------------------------------------------------------------------
__global__ __launch_bounds__(256)
void ln_kernel(const float* __restrict__ h, const float* __restrict__ g,
               const float* __restrict__ bta, bf16_t* __restrict__ out)
{
  int t = threadIdx.x;
  int lane = t & 63;
  long row = (long)blockIdx.x * 4 + (t >> 6);
  const float* hp = h + row * 256 + lane * 4;
  float4 v = *(const float4*)hp;
  float s = v.x + v.y + v.z + v.w;
  float q = v.x * v.x + v.y * v.y + v.z * v.z + v.w * v.w;
#pragma unroll
  for (int m = 32; m >= 1; m >>= 1) {
    s += __shfl_xor(s, m);
    q += __shfl_xor(q, m);
  }
  float mean = s * 0.00390625f;
  float var = q * 0.00390625f - mean * mean;
  float rstd = rsqrtf(var + 1e-5f);
  int c = lane * 4;
  float4 gv = *(const float4*)(g + c);
  float4 bv = *(const float4*)(bta + c);
  bf16x4 o;
  o[0] = (bf16_t)((v.x - mean) * rstd * gv.x + bv.x);
  o[1] = (bf16_t)((v.y - mean) * rstd * gv.y + bv.y);
  o[2] = (bf16_t)((v.z - mean) * rstd * gv.z + bv.z);
  o[3] = (bf16_t)((v.w - mean) * rstd * gv.w + bv.w);
  *(bf16x4*)(out + row * 256 + c) = o;
}

// ---------------------------------------------------------------------------
// Embedding conv1: x[Bc,S] -> gelu(bn(conv1d k=7 pad=3)) -> h1p[Bc,S+4,128]
// ---------------------------------------------------------------------------
__global__ __launch_bounds__(256)
void conv1_kernel(const float* __restrict__ x, const float* __restrict__ w1,
                  const float* __restrict__ sc, const float* __restrict__ sb,
                  bf16_t* __restrict__ h1p)
{
  int b = blockIdx.x >> 6;
  int s0 = (blockIdx.x & 63) << 6;
  __shared__ float xs[70];
  __shared__ float ws[896];
  int t = threadIdx.x;
  if (t < 70) {
    int s = s0 + t - 3;
    xs[t] = (s >= 0 && s < 4096) ? x[(long)b * 4096 + s] : 0.f;
  }
  for (int i = t; i < 896; i += 256) ws[i] = w1[i];
  __syncthreads();
  int c = t & 127, so = t >> 7;
  float wr[7];
#pragma unroll
  for (int k = 0; k < 7; k++) wr[k] = ws[c * 7 + k];
  float scl = sc[c], sbv = sb[c];
  for (int p = 0; p < 32; p++) {
    int sl = p * 2 + so;
    float a = 0.f;
#pragma unroll
    for (int k = 0; k < 7; k++) a += xs[sl + k] * wr[k];
    a = geluf(a * scl + sbv);
    h1p[((long)b * 4100 + s0 + sl + 2) * 128 + c] = (bf16_t)a;
  }
}

// ---------------------------------------------------------------------------
// kv partial: per (b,h,chunk of 512 s): acc[f][d] += kp[s,f]*v[s,d]; +ksum.
// ---------------------------------------------------------------------------
__global__ __launch_bounds__(256)
void kv_partial(const bf16_t* __restrict__ qpkpv,
                float* __restrict__ pkv, float* __restrict__ pks)
{
  int bh = blockIdx.x >> 3, ch = blockIdx.x & 7;
  int b = bh >> 3, hh = bh & 7;
  int s0 = ch * 512;
  __shared__ float kps[32 * 64];
  __shared__ float vs[32 * 32];
  int t = threadIdx.x;
  int f = t & 63, dg = t >> 6;
  float acc[8] = {0.f, 0.f, 0.f, 0.f, 0.f, 0.f, 0.f, 0.f};
  float ks = 0.f;
  const int row = t >> 3, slot8 = (t & 7) * 8, slot4 = (t & 7) * 4;
  for (int sb = 0; sb < 512; sb += 32) {
    __syncthreads();
    {
      const bf16_t* rowp = qpkpv + ((long)b * 4096 + s0 + sb + row) * 1280;
      bf16x8 k8 = *(const bf16x8*)(rowp + 512 + hh * 64 + slot8);
#pragma unroll
      for (int j = 0; j < 8; j++) kps[row * 64 + slot8 + j] = (float)k8[j];
      bf16x4 v4 = *(const bf16x4*)(rowp + 1024 + hh * 32 + slot4);
#pragma unroll
      for (int j = 0; j < 4; j++) vs[row * 32 + slot4 + j] = (float)v4[j];
    }
    __syncthreads();
#pragma unroll 4
    for (int s = 0; s < 32; s++) {
      float kval = kps[s * 64 + f];
      float4 v0 = *(const float4*)&vs[s * 32 + dg * 8];
      float4 v1 = *(const float4*)&vs[s * 32 + dg * 8 + 4];
      acc[0] += kval * v0.x; acc[1] += kval * v0.y;
      acc[2] += kval * v0.z; acc[3] += kval * v0.w;
      acc[4] += kval * v1.x; acc[5] += kval * v1.y;
      acc[6] += kval * v1.z; acc[7] += kval * v1.w;
      ks += kval;
    }
  }
  long o = (long)blockIdx.x * 2048 + f * 32 + dg * 8;
#pragma unroll
  for (int j = 0; j < 8; j++) pkv[o + j] = acc[j];
  if (dg == 0) pks[blockIdx.x * 64 + f] = ks;
}

__global__ __launch_bounds__(256)
void kv_reduce(const float* __restrict__ pkv, const float* __restrict__ pks,
               float* __restrict__ kv, float* __restrict__ ksum, int nbh)
{
  long idx = (long)blockIdx.x * 256 + threadIdx.x;  // nbh*2048
  {
    int bh = (int)(idx >> 11), fd = (int)(idx & 2047);
    float s = 0.f;
#pragma unroll
    for (int ch = 0; ch < 8; ch++) s += pkv[((long)(bh * 8 + ch)) * 2048 + fd];
    kv[idx] = s;
  }
  if (idx < (long)nbh * 64) {
    int bh = (int)(idx >> 6), f = (int)(idx & 63);
    float s = 0.f;
#pragma unroll
    for (int ch = 0; ch < 8; ch++) s += pks[(bh * 8 + ch) * 64 + f];
    ksum[idx] = s;
  }
}

// ---------------------------------------------------------------------------
// combine: ao[s, h*32+d] = (qp[s,:] @ kv[:,d]) / (qp[s,:]@ksum + 1e-8)
// ---------------------------------------------------------------------------
__global__ __launch_bounds__(256, 2)
void combine_mfma(const bf16_t* __restrict__ qpkpv, const float* __restrict__ kv,
                  const float* __restrict__ ksum, bf16_t* __restrict__ ao)
{
  int bh = blockIdx.x >> 5;
  int s0 = (blockIdx.x & 31) << 7;
  int b = bh >> 3, hh = bh & 7;
  __shared__ bf16_t A_s[128 * 72];
  __shared__ bf16_t B_s[48 * 72];
  int t = threadIdx.x;
  for (int g = t; g < 1024; g += 256) {
    int row = g >> 3, slot = (g & 7) * 8;
    *(bf16x8*)&A_s[row * 72 + slot] =
        *(const bf16x8*)(qpkpv + ((long)b * 4096 + s0 + row) * 1280 + hh * 64 + slot);
  }
  for (int i = t; i < 2048; i += 256) {
    int f = i >> 5, d = i & 31;
    B_s[d * 72 + f] = (bf16_t)kv[(long)bh * 2048 + i];
  }
  if (t < 64) B_s[32 * 72 + t] = (bf16_t)ksum[bh * 64 + t];
  for (int i = t; i < 960; i += 256) {
    int n = 33 + (i >> 6), f = i & 63;
    B_s[n * 72 + f] = (bf16_t)0.f;
  }
  __syncthreads();
  int lane = t & 63, w = t >> 6;
  f32x4 acc[2][3];
#pragma unroll
  for (int i = 0; i < 2; i++)
#pragma unroll
    for (int j = 0; j < 3; j++) acc[i][j] = (f32x4){0.f, 0.f, 0.f, 0.f};
#pragma unroll
  for (int kt = 0; kt < 2; kt++) {
    int ko = kt * 32 + (lane >> 4) * 8;
    bf16x8 a[2], bb[3];
#pragma unroll
    for (int i = 0; i < 2; i++)
      a[i] = *(const bf16x8*)&A_s[(w * 32 + i * 16 + (lane & 15)) * 72 + ko];
#pragma unroll
    for (int i = 0; i < 3; i++)
      bb[i] = *(const bf16x8*)&B_s[(i * 16 + (lane & 15)) * 72 + ko];
#pragma unroll
    for (int mi = 0; mi < 2; mi++)
#pragma unroll
      for (int ni = 0; ni < 3; ni++)
        acc[mi][ni] = __builtin_amdgcn_mfma_f32_16x16x32_bf16(a[mi], bb[ni], acc[mi][ni], 0, 0, 0);
  }
  long sbase = (long)b * 4096 + s0;
#pragma unroll
  for (int mi = 0; mi < 2; mi++)
#pragma unroll
    for (int j = 0; j < 4; j++) {
      int r = w * 32 + mi * 16 + ((lane >> 4) << 2) + j;
      float den = __shfl(acc[mi][2][j], (lane & 48)) + 1e-8f;
#pragma unroll
      for (int ni = 0; ni < 2; ni++) {
        int d = ni * 16 + (lane & 15);
        ao[(sbase + r) * 256 + hh * 32 + d] = (bf16_t)(acc[mi][ni][j] / den);
      }
    }
}

// ---------------------------------------------------------------------------
// h fp32 -> h_padded bf16 [Bc, S+4, 256] (rows offset +2)
// ---------------------------------------------------------------------------
__global__ __launch_bounds__(256)
void cast_pad(const float* __restrict__ h, bf16_t* __restrict__ hp)
{
  long i8 = ((long)blockIdx.x * 256 + threadIdx.x) * 8;
  long r = i8 >> 8;
  int c = (int)(i8 & 255);
  int b = (int)(r >> 12), s = (int)(r & 4095);
  float4 v0 = *(const float4*)(h + i8);
  float4 v1 = *(const float4*)(h + i8 + 4);
  bf16x8 o;
  o[0] = (bf16_t)v0.x; o[1] = (bf16_t)v0.y; o[2] = (bf16_t)v0.z; o[3] = (bf16_t)v0.w;
  o[4] = (bf16_t)v1.x; o[5] = (bf16_t)v1.y; o[6] = (bf16_t)v1.z; o[7] = (bf16_t)v1.w;
  *(bf16x8*)(hp + ((long)b * 4100 + s + 2) * 256 + c) = o;
}

// ---------------------------------------------------------------------------
// Final conv (DH->1, k=3, pad=1) + sigmoid -> out [Bc,S] fp32
// ---------------------------------------------------------------------------
__global__ __launch_bounds__(256)
void conv_final(const bf16_t* __restrict__ hdp, const float* __restrict__ w2,
                const float* __restrict__ b2, float* __restrict__ out)
{
  __shared__ float ws[384];
  int t = threadIdx.x;
  for (int i = t; i < 384; i += 256) ws[i] = w2[i];  // [c][k]
  __syncthreads();
  long idx = (long)blockIdx.x * 256 + t;
  int b = (int)(idx >> 12);
  const bf16_t* base = hdp + ((long)b * 4098 + (idx & 4095)) * 128;
  float a = b2[0];
#pragma unroll
  for (int k = 0; k < 3; k++) {
#pragma unroll
    for (int c8 = 0; c8 < 16; c8++) {
      bf16x8 v = *(const bf16x8*)(base + k * 128 + c8 * 8);
#pragma unroll
      for (int j = 0; j < 8; j++) a += (float)v[j] * ws[(c8 * 8 + j) * 3 + k];
    }
  }
  out[idx] = 1.f / (1.f + __expf(-a));
}

// ---------------------------------------------------------------------------
// Prep kernels (once per launch)
// ---------------------------------------------------------------------------
__global__ __launch_bounds__(256)
void prep_weff(const float* __restrict__ wq, const float* __restrict__ wk,
               const float* __restrict__ wv, const float* __restrict__ bq,
               const float* __restrict__ bk, const float* __restrict__ bv,
               const float* __restrict__ rf, bf16_t* __restrict__ weff,
               float* __restrict__ beff)
{
  long idx = (long)blockIdx.x * 256 + threadIdx.x;  // 4*1280*256
  int d = (int)(idx & 255);
  long r = idx >> 8;
  int n = (int)(r % 1280);
  int l = (int)(r / 1280);
  float val;
  if (n < 1024) {
    int qk = n >> 9;
    int h = (n >> 6) & 7;
    int f = n & 63;
    const float* w = qk ? wk : wq;
    const float* rfh = rf + ((long)(l * 8 + h) * 32) * 64 + f;
    const float* wrow = w + ((long)l * 256 + d) * 256 + h * 32;
    float s = 0.f;
#pragma unroll
    for (int hd = 0; hd < 32; hd++) s += wrow[hd] * rfh[hd * 64];
    val = s;
  } else {
    val = wv[((long)l * 256 + d) * 256 + (n - 1024)];
  }
  weff[idx] = (bf16_t)val;
  if (idx < 4 * 1280) {
    int nn = (int)(idx % 1280);
    int ll = (int)(idx / 1280);
    float bvv;
    if (nn < 1024) {
      int qk = nn >> 9;
      int h = (nn >> 6) & 7;
      int f = nn & 63;
      const float* bsrc = qk ? bk : bq;
      float s = 0.f;
      for (int hd = 0; hd < 32; hd++)
        s += bsrc[ll * 256 + h * 32 + hd] * rf[((long)(ll * 8 + h) * 32 + hd) * 64 + f];
      bvv = s;
    } else {
      bvv = bv[ll * 256 + (nn - 1024)];
    }
    beff[idx] = bvv;
  }
}

__global__ __launch_bounds__(256)
void prep_cast_t(const float* __restrict__ src, bf16_t* __restrict__ dst, int K, int N)
{
  long idx = (long)blockIdx.x * 256 + threadIdx.x;  // nmats*N*K
  int k = (int)(idx % K);
  long r = idx / K;
  int n = (int)(r % N);
  int l = (int)(r / N);
  dst[idx] = (bf16_t)src[((long)l * K + k) * N + n];
}

__global__ __launch_bounds__(256)
void prep_conv_t(const float* __restrict__ w, bf16_t* __restrict__ dst, int C, int KW)
{
  long idx = (long)blockIdx.x * 256 + threadIdx.x;  // O*C*KW
  int ckw = C * KW;
  int kk = (int)(idx % ckw);
  int o = (int)(idx / ckw);
  int kw = kk / C, c = kk % C;
  dst[idx] = (bf16_t)w[((long)o * C + c) * KW + kw];
}

__global__ __launch_bounds__(256)
void prep_bn(const float* g1, const float* b1, const float* cb1,
             const float* g2, const float* b2, const float* cb2,
             const float* g3, const float* b3, const float* cb3,
             float* sc1, float* sb1, float* sc2, float* sb2,
             float* sc3, float* sb3)
{
  int t = threadIdx.x;
  const float r = rsqrtf(1.f + 1e-5f);
  if (t < 128) { float s = g1[t] * r; sc1[t] = s; sb1[t] = cb1[t] * s + b1[t]; }
  if (t < 256) { float s = g2[t] * r; sc2[t] = s; sb2[t] = cb2[t] * s + b2[t]; }
  if (t < 128) { float s = g3[t] * r; sc3[t] = s; sb3[t] = cb3[t] * s + b3[t]; }
}

__global__ __launch_bounds__(256)
void pe_fill(float* __restrict__ pe)
{
  long idx = (long)blockIdx.x * 256 + threadIdx.x;  // 4096*256
  int dcol = (int)(idx & 255);
  int s = (int)(idx >> 8);
  int i2 = dcol >> 1;
  float freq = expf(-9.210340371976184f * (float)(2 * i2) / 256.f);
  float a = (float)s * freq;
  pe[idx] = (dcol & 1) ? cosf(a) : sinf(a);
}

// ---------------------------------------------------------------------------
extern "C" void kernel_launch(void* const* d_in, const int* in_sizes, int n_in,
                              void* d_out, int out_size, void* d_ws, size_t ws_size,
                              hipStream_t stream)
{
  (void)in_sizes; (void)n_in; (void)out_size;
  const float* x      = (const float*)d_in[0];
  const float* emb_w1 = (const float*)d_in[1];
  const float* emb_b1 = (const float*)d_in[2];
  const float* bn1_g  = (const float*)d_in[3];
  const float* bn1_b  = (const float*)d_in[4];
  const float* emb_w2 = (const float*)d_in[5];
  const float* emb_b2 = (const float*)d_in[6];
  const float* bn2_g  = (const float*)d_in[7];
  const float* bn2_b  = (const float*)d_in[8];
  const float* wq     = (const float*)d_in[9];
  const float* bq     = (const float*)d_in[10];
  const float* wk     = (const float*)d_in[11];
  const float* bk     = (const float*)d_in[12];
  const float* wv     = (const float*)d_in[13];
  const float* bv     = (const float*)d_in[14];
  const float* wo     = (const float*)d_in[15];
  const float* bo     = (const float*)d_in[16];
  const float* rf     = (const float*)d_in[17];
  const float* ln1_g  = (const float*)d_in[18];
  const float* ln1_b  = (const float*)d_in[19];
  const float* ln2_g  = (const float*)d_in[20];
  const float* ln2_b  = (const float*)d_in[21];
  const float* ff_w1  = (const float*)d_in[22];
  const float* ff_b1  = (const float*)d_in[23];
  const float* ff_w2  = (const float*)d_in[24];
  const float* ff_b2  = (const float*)d_in[25];
  const float* dec_w1 = (const float*)d_in[26];
  const float* dec_b1 = (const float*)d_in[27];
  const float* bn3_g  = (const float*)d_in[28];
  const float* bn3_b  = (const float*)d_in[29];
  const float* dec_w2 = (const float*)d_in[30];
  const float* dec_b2 = (const float*)d_in[31];

  char* W = (char*)d_ws;

  // ---- fixed region (weights, ~12.2 MB; reserve 16 MB) ----
  bf16_t* weff = (bf16_t*)(W + 0);                     // 4*1280*256*2 = 2,621,440
  float*  beff = (float*)(W + 2621440);                // 20,480
  bf16_t* wot  = (bf16_t*)(W + 2641920);               // 524,288
  bf16_t* w1t  = (bf16_t*)(W + 3166208);               // 2,097,152
  bf16_t* w2t  = (bf16_t*)(W + 5263360);               // 2,097,152
  bf16_t* c2t  = (bf16_t*)(W + 7360512);               // 327,680
  bf16_t* d1t  = (bf16_t*)(W + 7688192);               // 327,680
  float*  pe   = (float*)(W + 8015872);                // 4,194,304
  float*  sc1  = (float*)(W + 12210176);
  float*  sb1  = (float*)(W + 12211200);
  float*  sc2  = (float*)(W + 12212224);
  float*  sb2  = (float*)(W + 12213248);
  float*  sc3  = (float*)(W + 12214272);
  float*  sb3  = (float*)(W + 12215296);
  const size_t FIXED_END = 16777216;

  // ---- pick batch chunk Bc so workspace fits ws_size ----
  const size_t PER_B = 17385472;
  int Bc = 32;
  while (Bc > 1 && FIXED_END + (size_t)Bc * PER_B > ws_size) Bc >>= 1;

  char* P = W + FIXED_END;
  float*  h     = (float*)P;
  bf16_t* xa    = (bf16_t*)(P + (size_t)Bc * 4194304);
  bf16_t* ao    = xa;  // xa dead after fused qkv gemm; ao dead before ln2
  char*   big   = P + (size_t)Bc * (4194304 + 2097152);
  bf16_t* qpkpv = (bf16_t*)big;
  bf16_t* f1    = (bf16_t*)big;                               // after qpkpv dead
  bf16_t* h1p   = (bf16_t*)big;                               // pre-loop
  bf16_t* hpad  = (bf16_t*)big;                               // post-loop
  bf16_t* hdp   = (bf16_t*)(big + (size_t)Bc * 4100 * 256 * 2);
  float*  pkv   = (float*)(big + (size_t)Bc * 10485760);
  float*  pks   = (float*)((char*)pkv + (size_t)Bc * 524288);
  float*  kvb   = (float*)((char*)pks + (size_t)Bc * 16384);
  float*  ksum  = (float*)((char*)kvb + (size_t)Bc * 65536);

  // ---- weight prep (once) ----
  prep_weff<<<5120, 256, 0, stream>>>(wq, wk, wv, bq, bk, bv, rf, weff, beff);
  prep_cast_t<<<1024, 256, 0, stream>>>(wo, wot, 256, 256);
  prep_cast_t<<<4096, 256, 0, stream>>>(ff_w1, w1t, 256, 1024);
  prep_cast_t<<<4096, 256, 0, stream>>>(ff_w2, w2t, 1024, 256);
  prep_conv_t<<<640, 256, 0, stream>>>(emb_w2, c2t, 128, 5);
  prep_conv_t<<<640, 256, 0, stream>>>(dec_w1, d1t, 256, 5);
  prep_bn<<<1, 256, 0, stream>>>(bn1_g, bn1_b, emb_b1, bn2_g, bn2_b, emb_b2,
                                 bn3_g, bn3_b, dec_b1, sc1, sb1, sc2, sb2, sc3, sb3);
  pe_fill<<<4096, 256, 0, stream>>>(pe);

  for (int c0 = 0; c0 < 32; c0 += Bc) {
    const float* xc = x + (size_t)c0 * 4096;

    // ---- embedding ----
    hipMemsetAsync(h1p, 0, (size_t)Bc * 4100 * 128 * 2, stream);
    conv1_kernel<<<Bc * 64, 256, 0, stream>>>(xc, emb_w1, sc1, sb1, h1p);
    gemm_bf16<3><<<dim3(Bc * 32, 2), 256, 0, stream>>>(
        h1p, c2t, h, sb2, sc2, nullptr, pe,
        640, 128, 4100L * 128, 4096, 256, 256, 4096L * 256, 0);

    // ---- transformer layers ----
    for (int l = 0; l < 4; l++) {
      ln_kernel<<<Bc * 1024, 256, 0, stream>>>(h, ln1_g + l * 256, ln1_b + l * 256, xa);
      gemm_bf16<5><<<dim3(Bc * 32, 10), 256, 0, stream>>>(
          xa, weff + (long)l * 327680, qpkpv, beff + l * 1280, nullptr, nullptr, nullptr,
          256, 256, 4096L * 256, 4096, 1280, 1280, 4096L * 1280, 0);
      kv_partial<<<Bc * 64, 256, 0, stream>>>(qpkpv, pkv, pks);
      kv_reduce<<<Bc * 64, 256, 0, stream>>>(pkv, pks, kvb, ksum, Bc * 8);
      combine_mfma<<<Bc * 256, 256, 0, stream>>>(qpkpv, kvb, ksum, ao);
      gemm_bf16<1><<<dim3(Bc * 32, 2), 256, 0, stream>>>(
          ao, wot + (long)l * 65536, h, bo + l * 256, nullptr, h, nullptr,
          256, 256, 4096L * 256, 4096, 256, 256, 4096L * 256, 0);
      ln_kernel<<<Bc * 1024, 256, 0, stream>>>(h, ln2_g + l * 256, ln2_b + l * 256, xa);
      gemm_bf16<2><<<dim3(Bc * 32, 8), 256, 0, stream>>>(
          xa, w1t + (long)l * 262144, f1, ff_b1 + l * 1024, nullptr, nullptr, nullptr,
          256, 256, 4096L * 256, 4096, 1024, 1024, 4096L * 1024, 0);
      gemm_bf16<1><<<dim3(Bc * 32, 2), 256, 0, stream>>>(
          f1, w2t + (long)l * 262144, h, ff_b2 + l * 256, nullptr, h, nullptr,
          1024, 1024, 4096L * 1024, 4096, 256, 256, 4096L * 256, 0);
    }

    // ---- decoder ----
    hipMemsetAsync(hpad, 0, (size_t)Bc * 4100 * 256 * 2, stream);
    cast_pad<<<Bc * 512, 256, 0, stream>>>(h, hpad);
    hipMemsetAsync(hdp, 0, (size_t)Bc * 4098 * 128 * 2, stream);
    gemm_bf16<4><<<dim3(Bc * 32, 1), 256, 0, stream>>>(
        hpad, d1t, hdp, sb3, sc3, nullptr, nullptr,
        1280, 256, 4100L * 256, 4096, 128, 128, 4098L * 128, 1);
    conv_final<<<Bc * 16, 256, 0, stream>>>(hdp, dec_w2, dec_b2,
                                            (float*)d_out + (size_t)c0 * 4096);
  }
}

// Round 6
// 4479.372 us; speedup vs baseline: 1.5256x; 1.0011x over previous
//
#include <hip/hip_runtime.h>
#include <hip/hip_bf16.h>
#include <math.h>

// ============================================================================
// PPGPeakPerformer forward on MI355X (gfx950)
// B=32 S=4096 D=256 DH=128 H=8 HD=32 F=64 L=4
// GEMM: 128x128 tile, BK=32, triple-buffered LDS, depth-2 prefetch, counted
// s_waitcnt vmcnt(4) + raw s_barrier (T3+T4), K templated -> full unroll,
// setprio around MFMA (T5). Swizzle slot^((row>>1)&3) both-sides (2-way only,
// free). Fast rational erf. Fused q/k RF projection GEMM.
// ============================================================================

typedef __bf16 bf16_t;
typedef __bf16 bf16x8 __attribute__((ext_vector_type(8)));
typedef __bf16 bf16x4 __attribute__((ext_vector_type(4)));
typedef float  f32x4  __attribute__((ext_vector_type(4)));

#define DEV __device__ __forceinline__

DEV float erf_fast(float x) {
  float ax = fabsf(x);
  float t = __builtin_amdgcn_rcpf(1.f + 0.3275911f * ax);
  float p = t * (0.254829592f + t * (-0.284496736f + t * (1.421413741f +
            t * (-1.453152027f + t * 1.061405429f))));
  float r = 1.f - p * __expf(-ax * ax);
  return copysignf(r, x);
}
DEV float geluf(float v) { return 0.5f * v * (1.f + erf_fast(v * 0.70710678118654752440f)); }
DEV float softplusf(float v) {
  float e = __expf(-fabsf(v));
  return fmaxf(v, 0.f) + __logf(1.f + e);
}

// Direct global->LDS 16B staging. LDS dest is wave-uniform base + lane*16.
DEV void gload16(const bf16_t* g, bf16_t* l) {
  __builtin_amdgcn_global_load_lds(
      (const __attribute__((address_space(1))) void*)g,
      (__attribute__((address_space(3))) void*)l, 16, 0, 0);
}

// ---------------------------------------------------------------------------
// GEMM: C[m,n] = sum_k A[m,k]*Bt[n,k].  A bf16 (batched rows), Bt bf16 [N][K].
// EPI: 1 = +bias +resid -> fp32; 2 = gelu(+bias) -> bf16;
//      3 = gelu(scale*x+bias)+pe -> fp32; 4 = gelu(scale*x+bias) -> bf16;
//      5 = col<1024 ? softplus(+bias) : (+bias) -> bf16
// BK=32 (64B rows = 4x16B slots). Swizzle: LDS slot = src_slot ^ ((row>>1)&3)
// (rows 0..7 cover all 4 slots per bank-half -> only free 2-way aliasing).
// Staged via gload16 with pre-swizzled per-lane source; LDS dest linear.
// Triple buffer, depth-2 prefetch, vmcnt(4) counted wait; K templated so the
// whole pipeline is fully unrolled (addresses fold to immediates).
// ---------------------------------------------------------------------------
template <int EPI, int K>
__global__ __launch_bounds__(256, 3)
void gemm_bf16(const bf16_t* __restrict__ A, const bf16_t* __restrict__ Bt,
               void* Cout, const float* __restrict__ bias,
               const float* __restrict__ scale, const float* resid,
               const float* __restrict__ pe,
               int lda, long a_bstride, int rpb,
               int N, int ldc, long c_bstride, int c_roff)
{
  __shared__ bf16_t As[3][128 * 32];
  __shared__ bf16_t Bs[3][128 * 32];
  const int t = threadIdx.x;
  const int lane = t & 63;
  const int w = t >> 6;
  const int wm = w >> 1, wn = w & 1;
  const long m0 = (long)blockIdx.x * 128;
  const int n0 = blockIdx.y * 128;
  const int b = (int)(m0 / rpb);
  const int s_base = (int)(m0 % rpb);
  const bf16_t* Ab = A + (long)b * a_bstride + (long)s_base * lda;
  const bf16_t* Bb = Bt + (long)n0 * K;

  // staging source (pre-swizzled): lane covers row (lane>>2) of a 16-row
  // block, 16B slot ((lane&3) ^ ((row>>1)&3)).
  const int srow = lane >> 2;
  const int sslot = (lane & 3) ^ ((srow >> 1) & 3);
  const bf16_t* aS = Ab + (long)(w * 32 + srow) * lda + sslot * 8;
  const bf16_t* bS = Bb + (long)(w * 32 + srow) * K + sslot * 8;
  const int dsto = w * 1024;  // 32 rows x 32 elems per wave

#define STAGE(bufidx, kk)                                   \
  {                                                         \
    bf16_t* a_ = &As[bufidx][dsto];                         \
    bf16_t* b_ = &Bs[bufidx][dsto];                         \
    gload16(aS + (kk), a_);                                 \
    gload16(aS + (kk) + 16 * (long)lda, a_ + 512);          \
    gload16(bS + (kk), b_);                                 \
    gload16(bS + (kk) + 16 * (long)K, b_ + 512);            \
  }

  f32x4 acc[4][4];
#pragma unroll
  for (int i = 0; i < 4; i++)
#pragma unroll
    for (int j = 0; j < 4; j++) acc[i][j] = (f32x4){0.f, 0.f, 0.f, 0.f};

  constexpr int NT = K >> 5;
  STAGE(0, 0);
  STAGE(1, 32);

#pragma unroll
  for (int tt = 0; tt < NT; ++tt) {
    if (tt + 1 < NT) {
      asm volatile("s_waitcnt vmcnt(4)" ::: "memory");
    } else {
      asm volatile("s_waitcnt vmcnt(0)" ::: "memory");
    }
    __builtin_amdgcn_s_barrier();
    __builtin_amdgcn_sched_barrier(0);
    if (tt + 2 < NT) STAGE((tt + 2) % 3, (tt + 2) * 32);
    const int cb = tt % 3;
    const bf16_t* Acur = As[cb];
    const bf16_t* Bcur = Bs[cb];
    const int kb = (lane >> 4) * 16;
    bf16x8 af[4], bfr[4];
#pragma unroll
    for (int i = 0; i < 4; i++) {
      int rA = wm * 64 + i * 16 + (lane & 15);
      af[i] = *(const bf16x8*)((const char*)Acur + rA * 64 + (kb ^ (((rA >> 1) & 3) << 4)));
      int rB = wn * 64 + i * 16 + (lane & 15);
      bfr[i] = *(const bf16x8*)((const char*)Bcur + rB * 64 + (kb ^ (((rB >> 1) & 3) << 4)));
    }
    __builtin_amdgcn_s_setprio(1);
#pragma unroll
    for (int mi = 0; mi < 4; mi++)
#pragma unroll
      for (int ni = 0; ni < 4; ni++)
        acc[mi][ni] = __builtin_amdgcn_mfma_f32_16x16x32_bf16(af[mi], bfr[ni], acc[mi][ni], 0, 0, 0);
    __builtin_amdgcn_s_setprio(0);
  }
#undef STAGE

  const int colbase = n0 + wn * 64 + (lane & 15);
  float bias_r[4], scale_r[4];
#pragma unroll
  for (int ni = 0; ni < 4; ni++) {
    int col = colbase + ni * 16;
    bias_r[ni] = bias[col];
    scale_r[ni] = (EPI == 3 || EPI == 4) ? scale[col] : 0.f;
  }
#pragma unroll
  for (int mi = 0; mi < 4; mi++) {
#pragma unroll
    for (int j = 0; j < 4; j++) {
      int row = wm * 64 + mi * 16 + ((lane >> 4) << 2) + j;
      long s = s_base + row;
      long cro = (long)b * c_bstride + (s + c_roff) * (long)ldc;
#pragma unroll
      for (int ni = 0; ni < 4; ni++) {
        int col = colbase + ni * 16;
        float v = acc[mi][ni][j];
        if constexpr (EPI == 1) {
          v += bias_r[ni] + resid[cro + col];
          ((float*)Cout)[cro + col] = v;
        } else if constexpr (EPI == 2) {
          v = geluf(v + bias_r[ni]);
          ((bf16_t*)Cout)[cro + col] = (bf16_t)v;
        } else if constexpr (EPI == 3) {
          v = geluf(v * scale_r[ni] + bias_r[ni]) + pe[s * 256 + col];
          ((float*)Cout)[cro + col] = v;
        } else if constexpr (EPI == 4) {
          v = geluf(v * scale_r[ni] + bias_r[ni]);
          ((bf16_t*)Cout)[cro + col] = (bf16_t)v;
        } else {  // 5
          v += bias_r[ni];
          if (col < 1024) v = softplusf(v);
          ((bf16_t*)Cout)[cro + col] = (bf16_t)v;
        }
      }
    }
  }
}

// ---------------------------------------------------------------------------
// LayerNorm over D=256, fp32 in -> bf16 out. 4 rows/block (1 wave per row).
// ---------------------------------------------------------------------------
__global__ __launch_bounds__(256)
void ln_kernel(const float* __restrict__ h, const float* __restrict__ g,
               const float* __restrict__ bta, bf16_t* __restrict__ out)
{
  int t = threadIdx.x;
  int lane = t & 63;
  long row = (long)blockIdx.x * 4 + (t >> 6);
  const float* hp = h + row * 256 + lane * 4;
  float4 v = *(const float4*)hp;
  float s = v.x + v.y + v.z + v.w;
  float q = v.x * v.x + v.y * v.y + v.z * v.z + v.w * v.w;
#pragma unroll
  for (int m = 32; m >= 1; m >>= 1) {
    s += __shfl_xor(s, m);
    q += __shfl_xor(q, m);
  }
  float mean = s * 0.00390625f;
  float var = q * 0.00390625f - mean * mean;
  float rstd = rsqrtf(var + 1e-5f);
  int c = lane * 4;
  float4 gv = *(const float4*)(g + c);
  float4 bv = *(const float4*)(bta + c);
  bf16x4 o;
  o[0] = (bf16_t)((v.x - mean) * rstd * gv.x + bv.x);
  o[1] = (bf16_t)((v.y - mean) * rstd * gv.y + bv.y);
  o[2] = (bf16_t)((v.z - mean) * rstd * gv.z + bv.z);
  o[3] = (bf16_t)((v.w - mean) * rstd * gv.w + bv.w);
  *(bf16x4*)(out + row * 256 + c) = o;
}

// ---------------------------------------------------------------------------
// Embedding conv1: x[Bc,S] -> gelu(bn(conv1d k=7 pad=3)) -> h1p[Bc,S+4,128]
// ---------------------------------------------------------------------------
__global__ __launch_bounds__(256)
void conv1_kernel(const float* __restrict__ x, const float* __restrict__ w1,
                  const float* __restrict__ sc, const float* __restrict__ sb,
                  bf16_t* __restrict__ h1p)
{
  int b = blockIdx.x >> 6;
  int s0 = (blockIdx.x & 63) << 6;
  __shared__ float xs[70];
  __shared__ float ws[896];
  int t = threadIdx.x;
  if (t < 70) {
    int s = s0 + t - 3;
    xs[t] = (s >= 0 && s < 4096) ? x[(long)b * 4096 + s] : 0.f;
  }
  for (int i = t; i < 896; i += 256) ws[i] = w1[i];
  __syncthreads();
  int c = t & 127, so = t >> 7;
  float wr[7];
#pragma unroll
  for (int k = 0; k < 7; k++) wr[k] = ws[c * 7 + k];
  float scl = sc[c], sbv = sb[c];
  for (int p = 0; p < 32; p++) {
    int sl = p * 2 + so;
    float a = 0.f;
#pragma unroll
    for (int k = 0; k < 7; k++) a += xs[sl + k] * wr[k];
    a = geluf(a * scl + sbv);
    h1p[((long)b * 4100 + s0 + sl + 2) * 128 + c] = (bf16_t)a;
  }
}

// ---------------------------------------------------------------------------
// kv partial: per (b,h,chunk of 512 s): acc[f][d] += kp[s,f]*v[s,d]; +ksum.
// ---------------------------------------------------------------------------
__global__ __launch_bounds__(256)
void kv_partial(const bf16_t* __restrict__ qpkpv,
                float* __restrict__ pkv, float* __restrict__ pks)
{
  int bh = blockIdx.x >> 3, ch = blockIdx.x & 7;
  int b = bh >> 3, hh = bh & 7;
  int s0 = ch * 512;
  __shared__ float kps[32 * 64];
  __shared__ float vs[32 * 32];
  int t = threadIdx.x;
  int f = t & 63, dg = t >> 6;
  float acc[8] = {0.f, 0.f, 0.f, 0.f, 0.f, 0.f, 0.f, 0.f};
  float ks = 0.f;
  const int row = t >> 3, slot8 = (t & 7) * 8, slot4 = (t & 7) * 4;
  for (int sb = 0; sb < 512; sb += 32) {
    __syncthreads();
    {
      const bf16_t* rowp = qpkpv + ((long)b * 4096 + s0 + sb + row) * 1280;
      bf16x8 k8 = *(const bf16x8*)(rowp + 512 + hh * 64 + slot8);
#pragma unroll
      for (int j = 0; j < 8; j++) kps[row * 64 + slot8 + j] = (float)k8[j];
      bf16x4 v4 = *(const bf16x4*)(rowp + 1024 + hh * 32 + slot4);
#pragma unroll
      for (int j = 0; j < 4; j++) vs[row * 32 + slot4 + j] = (float)v4[j];
    }
    __syncthreads();
#pragma unroll 4
    for (int s = 0; s < 32; s++) {
      float kval = kps[s * 64 + f];
      float4 v0 = *(const float4*)&vs[s * 32 + dg * 8];
      float4 v1 = *(const float4*)&vs[s * 32 + dg * 8 + 4];
      acc[0] += kval * v0.x; acc[1] += kval * v0.y;
      acc[2] += kval * v0.z; acc[3] += kval * v0.w;
      acc[4] += kval * v1.x; acc[5] += kval * v1.y;
      acc[6] += kval * v1.z; acc[7] += kval * v1.w;
      ks += kval;
    }
  }
  long o = (long)blockIdx.x * 2048 + f * 32 + dg * 8;
#pragma unroll
  for (int j = 0; j < 8; j++) pkv[o + j] = acc[j];
  if (dg == 0) pks[blockIdx.x * 64 + f] = ks;
}

__global__ __launch_bounds__(256)
void kv_reduce(const float* __restrict__ pkv, const float* __restrict__ pks,
               float* __restrict__ kv, float* __restrict__ ksum, int nbh)
{
  long idx = (long)blockIdx.x * 256 + threadIdx.x;  // nbh*2048
  {
    int bh = (int)(idx >> 11), fd = (int)(idx & 2047);
    float s = 0.f;
#pragma unroll
    for (int ch = 0; ch < 8; ch++) s += pkv[((long)(bh * 8 + ch)) * 2048 + fd];
    kv[idx] = s;
  }
  if (idx < (long)nbh * 64) {
    int bh = (int)(idx >> 6), f = (int)(idx & 63);
    float s = 0.f;
#pragma unroll
    for (int ch = 0; ch < 8; ch++) s += pks[(bh * 8 + ch) * 64 + f];
    ksum[idx] = s;
  }
}

// ---------------------------------------------------------------------------
// combine: ao[s, h*32+d] = (qp[s,:] @ kv[:,d]) / (qp[s,:]@ksum + 1e-8)
// ---------------------------------------------------------------------------
__global__ __launch_bounds__(256, 2)
void combine_mfma(const bf16_t* __restrict__ qpkpv, const float* __restrict__ kv,
                  const float* __restrict__ ksum, bf16_t* __restrict__ ao)
{
  int bh = blockIdx.x >> 5;
  int s0 = (blockIdx.x & 31) << 7;
  int b = bh >> 3, hh = bh & 7;
  __shared__ bf16_t A_s[128 * 72];
  __shared__ bf16_t B_s[48 * 72];
  int t = threadIdx.x;
  for (int g = t; g < 1024; g += 256) {
    int row = g >> 3, slot = (g & 7) * 8;
    *(bf16x8*)&A_s[row * 72 + slot] =
        *(const bf16x8*)(qpkpv + ((long)b * 4096 + s0 + row) * 1280 + hh * 64 + slot);
  }
  for (int i = t; i < 2048; i += 256) {
    int f = i >> 5, d = i & 31;
    B_s[d * 72 + f] = (bf16_t)kv[(long)bh * 2048 + i];
  }
  if (t < 64) B_s[32 * 72 + t] = (bf16_t)ksum[bh * 64 + t];
  for (int i = t; i < 960; i += 256) {
    int n = 33 + (i >> 6), f = i & 63;
    B_s[n * 72 + f] = (bf16_t)0.f;
  }
  __syncthreads();
  int lane = t & 63, w = t >> 6;
  f32x4 acc[2][3];
#pragma unroll
  for (int i = 0; i < 2; i++)
#pragma unroll
    for (int j = 0; j < 3; j++) acc[i][j] = (f32x4){0.f, 0.f, 0.f, 0.f};
#pragma unroll
  for (int kt = 0; kt < 2; kt++) {
    int ko = kt * 32 + (lane >> 4) * 8;
    bf16x8 a[2], bb[3];
#pragma unroll
    for (int i = 0; i < 2; i++)
      a[i] = *(const bf16x8*)&A_s[(w * 32 + i * 16 + (lane & 15)) * 72 + ko];
#pragma unroll
    for (int i = 0; i < 3; i++)
      bb[i] = *(const bf16x8*)&B_s[(i * 16 + (lane & 15)) * 72 + ko];
#pragma unroll
    for (int mi = 0; mi < 2; mi++)
#pragma unroll
      for (int ni = 0; ni < 3; ni++)
        acc[mi][ni] = __builtin_amdgcn_mfma_f32_16x16x32_bf16(a[mi], bb[ni], acc[mi][ni], 0, 0, 0);
  }
  long sbase = (long)b * 4096 + s0;
#pragma unroll
  for (int mi = 0; mi < 2; mi++)
#pragma unroll
    for (int j = 0; j < 4; j++) {
      int r = w * 32 + mi * 16 + ((lane >> 4) << 2) + j;
      float den = __shfl(acc[mi][2][j], (lane & 48)) + 1e-8f;
#pragma unroll
      for (int ni = 0; ni < 2; ni++) {
        int d = ni * 16 + (lane & 15);
        ao[(sbase + r) * 256 + hh * 32 + d] = (bf16_t)(acc[mi][ni][j] / den);
      }
    }
}

// ---------------------------------------------------------------------------
// h fp32 -> h_padded bf16 [Bc, S+4, 256] (rows offset +2)
// ---------------------------------------------------------------------------
__global__ __launch_bounds__(256)
void cast_pad(const float* __restrict__ h, bf16_t* __restrict__ hp)
{
  long i8 = ((long)blockIdx.x * 256 + threadIdx.x) * 8;
  long r = i8 >> 8;
  int c = (int)(i8 & 255);
  int b = (int)(r >> 12), s = (int)(r & 4095);
  float4 v0 = *(const float4*)(h + i8);
  float4 v1 = *(const float4*)(h + i8 + 4);
  bf16x8 o;
  o[0] = (bf16_t)v0.x; o[1] = (bf16_t)v0.y; o[2] = (bf16_t)v0.z; o[3] = (bf16_t)v0.w;
  o[4] = (bf16_t)v1.x; o[5] = (bf16_t)v1.y; o[6] = (bf16_t)v1.z; o[7] = (bf16_t)v1.w;
  *(bf16x8*)(hp + ((long)b * 4100 + s + 2) * 256 + c) = o;
}

// ---------------------------------------------------------------------------
// Final conv (DH->1, k=3, pad=1) + sigmoid -> out [Bc,S] fp32
// ---------------------------------------------------------------------------
__global__ __launch_bounds__(256)
void conv_final(const bf16_t* __restrict__ hdp, const float* __restrict__ w2,
                const float* __restrict__ b2, float* __restrict__ out)
{
  __shared__ float ws[384];
  int t = threadIdx.x;
  for (int i = t; i < 384; i += 256) ws[i] = w2[i];  // [c][k]
  __syncthreads();
  long idx = (long)blockIdx.x * 256 + t;
  int b = (int)(idx >> 12);
  const bf16_t* base = hdp + ((long)b * 4098 + (idx & 4095)) * 128;
  float a = b2[0];
#pragma unroll
  for (int k = 0; k < 3; k++) {
#pragma unroll
    for (int c8 = 0; c8 < 16; c8++) {
      bf16x8 v = *(const bf16x8*)(base + k * 128 + c8 * 8);
#pragma unroll
      for (int j = 0; j < 8; j++) a += (float)v[j] * ws[(c8 * 8 + j) * 3 + k];
    }
  }
  out[idx] = 1.f / (1.f + __expf(-a));
}

// ---------------------------------------------------------------------------
// Prep kernels (once per launch)
// ---------------------------------------------------------------------------
__global__ __launch_bounds__(256)
void prep_weff(const float* __restrict__ wq, const float* __restrict__ wk,
               const float* __restrict__ wv, const float* __restrict__ bq,
               const float* __restrict__ bk, const float* __restrict__ bv,
               const float* __restrict__ rf, bf16_t* __restrict__ weff,
               float* __restrict__ beff)
{
  long idx = (long)blockIdx.x * 256 + threadIdx.x;  // 4*1280*256
  int d = (int)(idx & 255);
  long r = idx >> 8;
  int n = (int)(r % 1280);
  int l = (int)(r / 1280);
  float val;
  if (n < 1024) {
    int qk = n >> 9;
    int h = (n >> 6) & 7;
    int f = n & 63;
    const float* w = qk ? wk : wq;
    const float* rfh = rf + ((long)(l * 8 + h) * 32) * 64 + f;
    const float* wrow = w + ((long)l * 256 + d) * 256 + h * 32;
    float s = 0.f;
#pragma unroll
    for (int hd = 0; hd < 32; hd++) s += wrow[hd] * rfh[hd * 64];
    val = s;
  } else {
    val = wv[((long)l * 256 + d) * 256 + (n - 1024)];
  }
  weff[idx] = (bf16_t)val;
  if (idx < 4 * 1280) {
    int nn = (int)(idx % 1280);
    int ll = (int)(idx / 1280);
    float bvv;
    if (nn < 1024) {
      int qk = nn >> 9;
      int h = (nn >> 6) & 7;
      int f = nn & 63;
      const float* bsrc = qk ? bk : bq;
      float s = 0.f;
      for (int hd = 0; hd < 32; hd++)
        s += bsrc[ll * 256 + h * 32 + hd] * rf[((long)(ll * 8 + h) * 32 + hd) * 64 + f];
      bvv = s;
    } else {
      bvv = bv[ll * 256 + (nn - 1024)];
    }
    beff[idx] = bvv;
  }
}

__global__ __launch_bounds__(256)
void prep_cast_t(const float* __restrict__ src, bf16_t* __restrict__ dst, int K, int N)
{
  long idx = (long)blockIdx.x * 256 + threadIdx.x;  // nmats*N*K
  int k = (int)(idx % K);
  long r = idx / K;
  int n = (int)(r % N);
  int l = (int)(r / N);
  dst[idx] = (bf16_t)src[((long)l * K + k) * N + n];
}

__global__ __launch_bounds__(256)
void prep_conv_t(const float* __restrict__ w, bf16_t* __restrict__ dst, int C, int KW)
{
  long idx = (long)blockIdx.x * 256 + threadIdx.x;  // O*C*KW
  int ckw = C * KW;
  int kk = (int)(idx % ckw);
  int o = (int)(idx / ckw);
  int kw = kk / C, c = kk % C;
  dst[idx] = (bf16_t)w[((long)o * C + c) * KW + kw];
}

__global__ __launch_bounds__(256)
void prep_bn(const float* g1, const float* b1, const float* cb1,
             const float* g2, const float* b2, const float* cb2,
             const float* g3, const float* b3, const float* cb3,
             float* sc1, float* sb1, float* sc2, float* sb2,
             float* sc3, float* sb3)
{
  int t = threadIdx.x;
  const float r = rsqrtf(1.f + 1e-5f);
  if (t < 128) { float s = g1[t] * r; sc1[t] = s; sb1[t] = cb1[t] * s + b1[t]; }
  if (t < 256) { float s = g2[t] * r; sc2[t] = s; sb2[t] = cb2[t] * s + b2[t]; }
  if (t < 128) { float s = g3[t] * r; sc3[t] = s; sb3[t] = cb3[t] * s + b3[t]; }
}

__global__ __launch_bounds__(256)
void pe_fill(float* __restrict__ pe)
{
  long idx = (long)blockIdx.x * 256 + threadIdx.x;  // 4096*256
  int dcol = (int)(idx & 255);
  int s = (int)(idx >> 8);
  int i2 = dcol >> 1;
  float freq = expf(-9.210340371976184f * (float)(2 * i2) / 256.f);
  float a = (float)s * freq;
  pe[idx] = (dcol & 1) ? cosf(a) : sinf(a);
}

// ---------------------------------------------------------------------------
extern "C" void kernel_launch(void* const* d_in, const int* in_sizes, int n_in,
                              void* d_out, int out_size, void* d_ws, size_t ws_size,
                              hipStream_t stream)
{
  (void)in_sizes; (void)n_in; (void)out_size;
  const float* x      = (const float*)d_in[0];
  const float* emb_w1 = (const float*)d_in[1];
  const float* emb_b1 = (const float*)d_in[2];
  const float* bn1_g  = (const float*)d_in[3];
  const float* bn1_b  = (const float*)d_in[4];
  const float* emb_w2 = (const float*)d_in[5];
  const float* emb_b2 = (const float*)d_in[6];
  const float* bn2_g  = (const float*)d_in[7];
  const float* bn2_b  = (const float*)d_in[8];
  const float* wq     = (const float*)d_in[9];
  const float* bq     = (const float*)d_in[10];
  const float* wk     = (const float*)d_in[11];
  const float* bk     = (const float*)d_in[12];
  const float* wv     = (const float*)d_in[13];
  const float* bv     = (const float*)d_in[14];
  const float* wo     = (const float*)d_in[15];
  const float* bo     = (const float*)d_in[16];
  const float* rf     = (const float*)d_in[17];
  const float* ln1_g  = (const float*)d_in[18];
  const float* ln1_b  = (const float*)d_in[19];
  const float* ln2_g  = (const float*)d_in[20];
  const float* ln2_b  = (const float*)d_in[21];
  const float* ff_w1  = (const float*)d_in[22];
  const float* ff_b1  = (const float*)d_in[23];
  const float* ff_w2  = (const float*)d_in[24];
  const float* ff_b2  = (const float*)d_in[25];
  const float* dec_w1 = (const float*)d_in[26];
  const float* dec_b1 = (const float*)d_in[27];
  const float* bn3_g  = (const float*)d_in[28];
  const float* bn3_b  = (const float*)d_in[29];
  const float* dec_w2 = (const float*)d_in[30];
  const float* dec_b2 = (const float*)d_in[31];

  char* W = (char*)d_ws;

  // ---- fixed region (weights, ~12.2 MB; reserve 16 MB) ----
  bf16_t* weff = (bf16_t*)(W + 0);                     // 4*1280*256*2 = 2,621,440
  float*  beff = (float*)(W + 2621440);                // 20,480
  bf16_t* wot  = (bf16_t*)(W + 2641920);               // 524,288
  bf16_t* w1t  = (bf16_t*)(W + 3166208);               // 2,097,152
  bf16_t* w2t  = (bf16_t*)(W + 5263360);               // 2,097,152
  bf16_t* c2t  = (bf16_t*)(W + 7360512);               // 327,680
  bf16_t* d1t  = (bf16_t*)(W + 7688192);               // 327,680
  float*  pe   = (float*)(W + 8015872);                // 4,194,304
  float*  sc1  = (float*)(W + 12210176);
  float*  sb1  = (float*)(W + 12211200);
  float*  sc2  = (float*)(W + 12212224);
  float*  sb2  = (float*)(W + 12213248);
  float*  sc3  = (float*)(W + 12214272);
  float*  sb3  = (float*)(W + 12215296);
  const size_t FIXED_END = 16777216;

  // ---- pick batch chunk Bc so workspace fits ws_size ----
  const size_t PER_B = 17385472;
  int Bc = 32;
  while (Bc > 1 && FIXED_END + (size_t)Bc * PER_B > ws_size) Bc >>= 1;

  char* P = W + FIXED_END;
  float*  h     = (float*)P;
  bf16_t* xa    = (bf16_t*)(P + (size_t)Bc * 4194304);
  bf16_t* ao    = xa;  // xa dead after fused qkv gemm; ao dead before ln2
  char*   big   = P + (size_t)Bc * (4194304 + 2097152);
  bf16_t* qpkpv = (bf16_t*)big;
  bf16_t* f1    = (bf16_t*)big;                               // after qpkpv dead
  bf16_t* h1p   = (bf16_t*)big;                               // pre-loop
  bf16_t* hpad  = (bf16_t*)big;                               // post-loop
  bf16_t* hdp   = (bf16_t*)(big + (size_t)Bc * 4100 * 256 * 2);
  float*  pkv   = (float*)(big + (size_t)Bc * 10485760);
  float*  pks   = (float*)((char*)pkv + (size_t)Bc * 524288);
  float*  kvb   = (float*)((char*)pks + (size_t)Bc * 16384);
  float*  ksum  = (float*)((char*)kvb + (size_t)Bc * 65536);

  // ---- weight prep (once) ----
  prep_weff<<<5120, 256, 0, stream>>>(wq, wk, wv, bq, bk, bv, rf, weff, beff);
  prep_cast_t<<<1024, 256, 0, stream>>>(wo, wot, 256, 256);
  prep_cast_t<<<4096, 256, 0, stream>>>(ff_w1, w1t, 256, 1024);
  prep_cast_t<<<4096, 256, 0, stream>>>(ff_w2, w2t, 1024, 256);
  prep_conv_t<<<640, 256, 0, stream>>>(emb_w2, c2t, 128, 5);
  prep_conv_t<<<640, 256, 0, stream>>>(dec_w1, d1t, 256, 5);
  prep_bn<<<1, 256, 0, stream>>>(bn1_g, bn1_b, emb_b1, bn2_g, bn2_b, emb_b2,
                                 bn3_g, bn3_b, dec_b1, sc1, sb1, sc2, sb2, sc3, sb3);
  pe_fill<<<4096, 256, 0, stream>>>(pe);

  for (int c0 = 0; c0 < 32; c0 += Bc) {
    const float* xc = x + (size_t)c0 * 4096;

    // ---- embedding ----
    hipMemsetAsync(h1p, 0, (size_t)Bc * 4100 * 128 * 2, stream);
    conv1_kernel<<<Bc * 64, 256, 0, stream>>>(xc, emb_w1, sc1, sb1, h1p);
    gemm_bf16<3, 640><<<dim3(Bc * 32, 2), 256, 0, stream>>>(
        h1p, c2t, h, sb2, sc2, nullptr, pe,
        128, 4100L * 128, 4096, 256, 256, 4096L * 256, 0);

    // ---- transformer layers ----
    for (int l = 0; l < 4; l++) {
      ln_kernel<<<Bc * 1024, 256, 0, stream>>>(h, ln1_g + l * 256, ln1_b + l * 256, xa);
      gemm_bf16<5, 256><<<dim3(Bc * 32, 10), 256, 0, stream>>>(
          xa, weff + (long)l * 327680, qpkpv, beff + l * 1280, nullptr, nullptr, nullptr,
          256, 4096L * 256, 4096, 1280, 1280, 4096L * 1280, 0);
      kv_partial<<<Bc * 64, 256, 0, stream>>>(qpkpv, pkv, pks);
      kv_reduce<<<Bc * 64, 256, 0, stream>>>(pkv, pks, kvb, ksum, Bc * 8);
      combine_mfma<<<Bc * 256, 256, 0, stream>>>(qpkpv, kvb, ksum, ao);
      gemm_bf16<1, 256><<<dim3(Bc * 32, 2), 256, 0, stream>>>(
          ao, wot + (long)l * 65536, h, bo + l * 256, nullptr, h, nullptr,
          256, 4096L * 256, 4096, 256, 256, 4096L * 256, 0);
      ln_kernel<<<Bc * 1024, 256, 0, stream>>>(h, ln2_g + l * 256, ln2_b + l * 256, xa);
      gemm_bf16<2, 256><<<dim3(Bc * 32, 8), 256, 0, stream>>>(
          xa, w1t + (long)l * 262144, f1, ff_b1 + l * 1024, nullptr, nullptr, nullptr,
          256, 4096L * 256, 4096, 1024, 1024, 4096L * 1024, 0);
      gemm_bf16<1, 1024><<<dim3(Bc * 32, 2), 256, 0, stream>>>(
          f1, w2t + (long)l * 262144, h, ff_b2 + l * 256, nullptr, h, nullptr,
          1024, 4096L * 1024, 4096, 256, 256, 4096L * 256, 0);
    }

    // ---- decoder ----
    hipMemsetAsync(hpad, 0, (size_t)Bc * 4100 * 256 * 2, stream);
    cast_pad<<<Bc * 512, 256, 0, stream>>>(h, hpad);
    hipMemsetAsync(hdp, 0, (size_t)Bc * 4098 * 128 * 2, stream);
    gemm_bf16<4, 1280><<<dim3(Bc * 32, 1), 256, 0, stream>>>(
        hpad, d1t, hdp, sb3, sc3, nullptr, nullptr,
        256, 4100L * 256, 4096, 128, 128, 4098L * 128, 1);
    conv_final<<<Bc * 16, 256, 0, stream>>>(hdp, dec_w2, dec_b2,
                                            (float*)d_out + (size_t)c0 * 4096);
  }
}